// Round 1
// baseline (3049.726 us; speedup 1.0000x reference)
//
#include <hip/hip_runtime.h>
#include <math.h>

#define NN 50000
#define EE 600000
#define MOUT 10000

// ---------------- generic C[M,128] = A[M,128] @ W[128,128] + b (+gated residual) ----------------
__global__ __launch_bounds__(256) void matmul128(
    const float* __restrict__ A, const float* __restrict__ W,
    const float* __restrict__ bias, float* __restrict__ C,
    int M, int mode, const float* __restrict__ skipv)
{
    __shared__ float a_tile[32][128];
    const int t = threadIdx.x;
    const int row0 = blockIdx.x * 32;
    #pragma unroll
    for (int i = 0; i < 4; ++i) {
        int li = t + i * 256;          // float4 index within 32x128 tile
        int r = li >> 5, c4 = li & 31;
        float4 val = make_float4(0.f, 0.f, 0.f, 0.f);
        if (row0 + r < M)
            val = ((const float4*)A)[(size_t)(row0 + r) * 32 + c4];
        *(float4*)&a_tile[r][c4 * 4] = val;
    }
    __syncthreads();
    const int cg = t & 31;   // cols cg*4 .. cg*4+3
    const int rg = t >> 5;   // rows rg*4 .. rg*4+3
    float acc[4][4];
    #pragma unroll
    for (int i = 0; i < 4; ++i)
        #pragma unroll
        for (int j = 0; j < 4; ++j) acc[i][j] = 0.f;

    for (int kb = 0; kb < 128; kb += 4) {
        float4 a4[4];
        #pragma unroll
        for (int i = 0; i < 4; ++i) a4[i] = *(const float4*)&a_tile[rg * 4 + i][kb];
        #pragma unroll
        for (int kk = 0; kk < 4; ++kk) {
            float4 w4 = ((const float4*)W)[(size_t)(kb + kk) * 32 + cg];
            #pragma unroll
            for (int i = 0; i < 4; ++i) {
                float a = (kk == 0) ? a4[i].x : (kk == 1) ? a4[i].y : (kk == 2) ? a4[i].z : a4[i].w;
                acc[i][0] = fmaf(a, w4.x, acc[i][0]);
                acc[i][1] = fmaf(a, w4.y, acc[i][1]);
                acc[i][2] = fmaf(a, w4.z, acc[i][2]);
                acc[i][3] = fmaf(a, w4.w, acc[i][3]);
            }
        }
    }
    float4 b4 = ((const float4*)bias)[cg];
    float gate = 0.f;
    if (mode == 1) gate = 1.f / (1.f + expf(-skipv[0]));
    #pragma unroll
    for (int i = 0; i < 4; ++i) {
        int rr = row0 + rg * 4 + i;
        if (rr < M) {
            size_t ci = (size_t)rr * 32 + cg;
            float4 o;
            o.x = acc[i][0] + b4.x; o.y = acc[i][1] + b4.y;
            o.z = acc[i][2] + b4.z; o.w = acc[i][3] + b4.w;
            if (mode == 1) {
                float4 hold = ((const float4*)C)[ci];
                o.x = gate * o.x + (1.f - gate) * hold.x;
                o.y = gate * o.y + (1.f - gate) * hold.y;
                o.z = gate * o.z + (1.f - gate) * hold.z;
                o.w = gate * o.w + (1.f - gate) * hold.w;
            }
            ((float4*)C)[ci] = o;
        }
    }
}

// ---------------- BatchNorm (training-mode batch stats, biased var) ----------------
__global__ __launch_bounds__(128) void bn_stats_kernel(const float* __restrict__ h,
                                                       float* __restrict__ stats, int n)
{
    int c = threadIdx.x;
    int r0 = blockIdx.x * 128;
    int r1 = min(r0 + 128, n);
    float s = 0.f, s2 = 0.f;
    for (int r = r0; r < r1; ++r) {
        float v = h[(size_t)r * 128 + c];
        s += v; s2 += v * v;
    }
    atomicAdd(&stats[c], s);
    atomicAdd(&stats[128 + c], s2);
}

__global__ __launch_bounds__(256) void bn_apply_kernel(float* __restrict__ h,
    const float* __restrict__ stats, const float* __restrict__ gamma,
    const float* __restrict__ beta, int n)
{
    int i = blockIdx.x * 256 + threadIdx.x;      // float4 index
    if (i >= n * 32) return;
    int c4 = i & 31;
    float invN = 1.f / (float)n;
    float4 v = ((const float4*)h)[i];
    float o[4] = {v.x, v.y, v.z, v.w};
    #pragma unroll
    for (int j = 0; j < 4; ++j) {
        int c = c4 * 4 + j;
        float mu = stats[c] * invN;
        float var = stats[128 + c] * invN - mu * mu;
        o[j] = (o[j] - mu) * rsqrtf(var + 1e-5f) * gamma[c] + beta[c];
    }
    ((float4*)h)[i] = make_float4(o[0], o[1], o[2], o[3]);
}

// ---------------- q_rel[n,r,h,d] = sum_e q[n,h,e] * a_rel[r,h,d,e] ----------------
__global__ __launch_bounds__(128) void qrel_kernel(const float* __restrict__ q,
    const float* __restrict__ arel, float* __restrict__ qrel, int n)
{
    const int t = threadIdx.x;
    const int r = t >> 5, hh = (t >> 3) & 3, dg = t & 7;
    float4 a4[4][8];                 // a_rel[r][hh][dg*4+j][e], e-contiguous
    const float4* ar4 = (const float4*)arel;
    #pragma unroll
    for (int j = 0; j < 4; ++j) {
        int d = dg * 4 + j;
        #pragma unroll
        for (int ec = 0; ec < 8; ++ec)
            a4[j][ec] = ar4[(size_t)((r * 4 + hh) * 32 + d) * 8 + ec];
    }
    for (int node = blockIdx.x; node < n; node += gridDim.x) {
        const float4* q4 = (const float4*)(q + (size_t)node * 128 + hh * 32);
        float acc0 = 0.f, acc1 = 0.f, acc2 = 0.f, acc3 = 0.f;
        #pragma unroll
        for (int ec = 0; ec < 8; ++ec) {
            float4 qv = q4[ec];
            acc0 += qv.x*a4[0][ec].x + qv.y*a4[0][ec].y + qv.z*a4[0][ec].z + qv.w*a4[0][ec].w;
            acc1 += qv.x*a4[1][ec].x + qv.y*a4[1][ec].y + qv.z*a4[1][ec].z + qv.w*a4[1][ec].w;
            acc2 += qv.x*a4[2][ec].x + qv.y*a4[2][ec].y + qv.z*a4[2][ec].z + qv.w*a4[2][ec].w;
            acc3 += qv.x*a4[3][ec].x + qv.y*a4[3][ec].y + qv.z*a4[3][ec].z + qv.w*a4[3][ec].w;
        }
        ((float4*)qrel)[(size_t)(node * 4 + r) * 32 + hh * 8 + dg] =
            make_float4(acc0, acc1, acc2, acc3);
    }
}

// ---------------- segment state init ----------------
__global__ __launch_bounds__(256) void init_seg_kernel(unsigned int* __restrict__ smax,
                                                       float* __restrict__ denom, int n)
{
    int i = blockIdx.x * 256 + threadIdx.x;
    if (i < n) { smax[i] = 0x007FFFFFu; denom[i] = 0.f; }   // encode(-inf)
}

__global__ __launch_bounds__(256) void zero_kernel(float4* __restrict__ p, int n4)
{
    int i = blockIdx.x * 256 + threadIdx.x;
    if (i < n4) p[i] = make_float4(0.f, 0.f, 0.f, 0.f);
}

// ---------------- score + atomic max ----------------
__global__ __launch_bounds__(256) void score_kernel(const float* __restrict__ qrel,
    const float* __restrict__ k, const int* __restrict__ ei, const int* __restrict__ etype,
    const float* __restrict__ prel, float* __restrict__ score, unsigned int* __restrict__ smax,
    int E)
{
    int idx = blockIdx.x * 256 + threadIdx.x;
    if (idx >= E * 4) return;
    int e = idx >> 2, hh = idx & 3;
    int src = ei[e], dst = ei[E + e], r = etype[e];
    const float4* qr = (const float4*)(qrel + (size_t)(dst * 4 + r) * 128 + hh * 32);
    const float4* kk = (const float4*)(k + (size_t)src * 128 + hh * 32);
    float s = 0.f;
    #pragma unroll
    for (int i = 0; i < 8; ++i) {
        float4 a = qr[i], b = kk[i];
        s += a.x*b.x + a.y*b.y + a.z*b.z + a.w*b.w;
    }
    s *= prel[r * 4 + hh] * 0.17677669529663687f;   // 1/sqrt(32)
    score[idx] = s;
    unsigned int u = __float_as_uint(s);
    u = (u & 0x80000000u) ? ~u : (u | 0x80000000u);
    atomicMax(&smax[(size_t)(dst * 4 + r) * 4 + hh], u);
}

// ---------------- exp + denom ----------------
__global__ __launch_bounds__(256) void exp_kernel(float* __restrict__ score,
    const unsigned int* __restrict__ smax, float* __restrict__ denom,
    const int* __restrict__ ei, const int* __restrict__ etype, int E)
{
    int idx = blockIdx.x * 256 + threadIdx.x;
    if (idx >= E * 4) return;
    int e = idx >> 2, hh = idx & 3;
    int dst = ei[E + e], r = etype[e];
    size_t sh = (size_t)(dst * 4 + r) * 4 + hh;
    unsigned int u = smax[sh];
    float m = (u & 0x80000000u) ? __uint_as_float(u ^ 0x80000000u) : __uint_as_float(~u);
    float ev = expf(score[idx] - m);
    score[idx] = ev;
    atomicAdd(&denom[sh], ev);
}

// ---------------- agg[dst,rel,h,d] += alpha * v[src,h,d] ----------------
__global__ __launch_bounds__(256) void agg_kernel(const float* __restrict__ escore,
    const float* __restrict__ denom, const float* __restrict__ v,
    const int* __restrict__ ei, const int* __restrict__ etype,
    float* __restrict__ agg, int E)
{
    int idx = blockIdx.x * 256 + threadIdx.x;   // E*32 threads, one float4 each
    if (idx >= E * 32) return;
    int e = idx >> 5, dg = idx & 31;
    int src = ei[e], dst = ei[E + e], r = etype[e];
    int hh = dg >> 3;
    float alpha = escore[(size_t)e * 4 + hh] / denom[(size_t)(dst * 4 + r) * 4 + hh];
    float4 v4 = ((const float4*)(v + (size_t)src * 128))[dg];
    float* o = agg + (size_t)(dst * 4 + r) * 128 + dg * 4;
    atomicAdd(o + 0, alpha * v4.x);
    atomicAdd(o + 1, alpha * v4.y);
    atomicAdd(o + 2, alpha * v4.z);
    atomicAdd(o + 3, alpha * v4.w);
}

// ---------------- msg[n,h,e] = gelu( sum_{r,d} agg[n,r,h,d] * m_rel[r,h,d,e] ) ----------------
__global__ __launch_bounds__(128) void msg_kernel(const float* __restrict__ agg,
    const float* __restrict__ mrel, float* __restrict__ msg, int n)
{
    const int t = threadIdx.x;
    const int hh = t >> 5, r = (t >> 3) & 3, eg = t & 7;   // r in shuffle-reachable bits 3..4
    float4 m4[32];                    // m_rel[r][hh][d][eg*4..+3]
    const float4* mr4 = (const float4*)mrel;
    #pragma unroll
    for (int d = 0; d < 32; ++d)
        m4[d] = mr4[(size_t)((r * 4 + hh) * 32 + d) * 8 + eg];
    for (int node = blockIdx.x; node < n; node += gridDim.x) {
        const float4* ag4 = (const float4*)(agg + (size_t)(node * 4 + r) * 128 + hh * 32);
        float4 acc = make_float4(0.f, 0.f, 0.f, 0.f);
        #pragma unroll
        for (int dc = 0; dc < 8; ++dc) {
            float4 av = ag4[dc];
            acc.x += av.x*m4[dc*4+0].x + av.y*m4[dc*4+1].x + av.z*m4[dc*4+2].x + av.w*m4[dc*4+3].x;
            acc.y += av.x*m4[dc*4+0].y + av.y*m4[dc*4+1].y + av.z*m4[dc*4+2].y + av.w*m4[dc*4+3].y;
            acc.z += av.x*m4[dc*4+0].z + av.y*m4[dc*4+1].z + av.z*m4[dc*4+2].z + av.w*m4[dc*4+3].z;
            acc.w += av.x*m4[dc*4+0].w + av.y*m4[dc*4+1].w + av.z*m4[dc*4+2].w + av.w*m4[dc*4+3].w;
        }
        // reduce over r (lanes differing in bits 3,4 of lane id)
        acc.x += __shfl_xor(acc.x, 8);  acc.x += __shfl_xor(acc.x, 16);
        acc.y += __shfl_xor(acc.y, 8);  acc.y += __shfl_xor(acc.y, 16);
        acc.z += __shfl_xor(acc.z, 8);  acc.z += __shfl_xor(acc.z, 16);
        acc.w += __shfl_xor(acc.w, 8);  acc.w += __shfl_xor(acc.w, 16);
        if (r == 0) {
            float4 o;
            o.x = 0.5f * acc.x * (1.f + erff(acc.x * 0.70710678118654752f));
            o.y = 0.5f * acc.y * (1.f + erff(acc.y * 0.70710678118654752f));
            o.z = 0.5f * acc.z * (1.f + erff(acc.z * 0.70710678118654752f));
            o.w = 0.5f * acc.w * (1.f + erff(acc.w * 0.70710678118654752f));
            ((float4*)msg)[(size_t)node * 32 + hh * 8 + eg] = o;
        }
    }
}

// ---------------- final gather h[idx] ----------------
__global__ __launch_bounds__(256) void gather_kernel(const float* __restrict__ h,
    const int* __restrict__ idx, float* __restrict__ out, int m)
{
    int i = blockIdx.x * 256 + threadIdx.x;   // m*32 float4s
    if (i >= m * 32) return;
    int row = i >> 5, c4 = i & 31;
    ((float4*)out)[i] = ((const float4*)(h + (size_t)idx[row] * 128))[c4];
}

extern "C" void kernel_launch(void* const* d_in, const int* in_sizes, int n_in,
                              void* d_out, int out_size, void* d_ws, size_t ws_size,
                              hipStream_t stream)
{
    const float* x      = (const float*)d_in[0];
    const float* proj_w = (const float*)d_in[1];
    const float* proj_b = (const float*)d_in[2];
    const float* bn_g   = (const float*)d_in[3];
    const float* bn_b   = (const float*)d_in[4];
    const float* q_w    = (const float*)d_in[5];
    const float* q_b    = (const float*)d_in[6];
    const float* k_w    = (const float*)d_in[7];
    const float* k_b    = (const float*)d_in[8];
    const float* v_w    = (const float*)d_in[9];
    const float* v_b    = (const float*)d_in[10];
    const float* a_w    = (const float*)d_in[11];
    const float* a_b    = (const float*)d_in[12];
    const float* skip   = (const float*)d_in[13];
    const float* a_rel  = (const float*)d_in[14];
    const float* m_rel  = (const float*)d_in[15];
    const float* p_rel  = (const float*)d_in[16];
    const int* edge_index = (const int*)d_in[17];
    const int* edge_type  = (const int*)d_in[18];
    const int* idx        = (const int*)d_in[19];
    float* out = (float*)d_out;

    const int N = NN, E = EE;
    float* ws = (float*)d_ws;
    size_t o = 0;
    float* h  = ws + o;  o += (size_t)N * 128;
    float* q  = ws + o;  o += (size_t)N * 128;
    float* k  = ws + o;  o += (size_t)N * 128;
    float* v  = ws + o;  o += (size_t)N * 128;
    float* B1 = ws + o;  o += (size_t)N * 512;        // q_rel, then reused as agg
    float* score = ws + o; o += (size_t)E * 4;
    unsigned int* smax = (unsigned int*)(ws + o); o += (size_t)N * 16;
    float* denom = ws + o; o += (size_t)N * 16;
    float* msg = ws + o;   o += (size_t)N * 128;
    float* stats = ws + o; o += 256;

    const int mmGrid = (N + 31) / 32;

    // proj + BN
    matmul128<<<mmGrid, 256, 0, stream>>>(x, proj_w, proj_b, h, N, 0, nullptr);
    zero_kernel<<<1, 64, 0, stream>>>((float4*)stats, 64);
    bn_stats_kernel<<<(N + 127) / 128, 128, 0, stream>>>(h, stats, N);
    bn_apply_kernel<<<(N * 32 + 255) / 256, 256, 0, stream>>>(h, stats, bn_g, bn_b, N);

    for (int l = 0; l < 2; ++l) {
        const float* qwl = q_w + (size_t)l * 16384;
        const float* kwl = k_w + (size_t)l * 16384;
        const float* vwl = v_w + (size_t)l * 16384;
        const float* awl = a_w + (size_t)l * 16384;
        const float* arl = a_rel + (size_t)l * 16384;
        const float* mrl = m_rel + (size_t)l * 16384;

        matmul128<<<mmGrid, 256, 0, stream>>>(h, qwl, q_b + l * 128, q, N, 0, nullptr);
        matmul128<<<mmGrid, 256, 0, stream>>>(h, kwl, k_b + l * 128, k, N, 0, nullptr);
        matmul128<<<mmGrid, 256, 0, stream>>>(h, vwl, v_b + l * 128, v, N, 0, nullptr);

        qrel_kernel<<<2048, 128, 0, stream>>>(q, arl, B1, N);
        init_seg_kernel<<<(N * 16 + 255) / 256, 256, 0, stream>>>(smax, denom, N * 16);
        score_kernel<<<(E * 4 + 255) / 256, 256, 0, stream>>>(B1, k, edge_index, edge_type,
                                                              p_rel + l * 16, score, smax, E);
        exp_kernel<<<(E * 4 + 255) / 256, 256, 0, stream>>>(score, smax, denom,
                                                            edge_index, edge_type, E);
        zero_kernel<<<((N * 512 / 4) + 255) / 256, 256, 0, stream>>>((float4*)B1, N * 512 / 4);
        agg_kernel<<<(E * 32 + 255) / 256, 256, 0, stream>>>(score, denom, v,
                                                             edge_index, edge_type, B1, E);
        msg_kernel<<<2048, 128, 0, stream>>>(B1, mrl, msg, N);
        matmul128<<<mmGrid, 256, 0, stream>>>(msg, awl, a_b + l * 128, h, N, 1, skip + l);
    }

    gather_kernel<<<(MOUT * 32 + 255) / 256, 256, 0, stream>>>(h, idx, out, MOUT);
}

// Round 2
// 1126.002 us; speedup vs baseline: 2.7085x; 2.7085x over previous
//
#include <hip/hip_runtime.h>
#include <math.h>

#define NN 50000
#define EE 600000
#define MOUT 10000
#define DEGCAP 192

// ---------------- generic C[M,128] = A[M,128] @ W[128,128] + b (+gated residual) ----------------
__global__ __launch_bounds__(256) void matmul128(
    const float* __restrict__ A, const float* __restrict__ W,
    const float* __restrict__ bias, float* __restrict__ C,
    int M, int mode, const float* __restrict__ skipv)
{
    __shared__ float a_tile[32][128];
    const int t = threadIdx.x;
    const int row0 = blockIdx.x * 32;
    #pragma unroll
    for (int i = 0; i < 4; ++i) {
        int li = t + i * 256;          // float4 index within 32x128 tile
        int r = li >> 5, c4 = li & 31;
        float4 val = make_float4(0.f, 0.f, 0.f, 0.f);
        if (row0 + r < M)
            val = ((const float4*)A)[(size_t)(row0 + r) * 32 + c4];
        *(float4*)&a_tile[r][c4 * 4] = val;
    }
    __syncthreads();
    const int cg = t & 31;   // cols cg*4 .. cg*4+3
    const int rg = t >> 5;   // rows rg*4 .. rg*4+3
    float acc[4][4];
    #pragma unroll
    for (int i = 0; i < 4; ++i)
        #pragma unroll
        for (int j = 0; j < 4; ++j) acc[i][j] = 0.f;

    for (int kb = 0; kb < 128; kb += 4) {
        float4 a4[4];
        #pragma unroll
        for (int i = 0; i < 4; ++i) a4[i] = *(const float4*)&a_tile[rg * 4 + i][kb];
        #pragma unroll
        for (int kk = 0; kk < 4; ++kk) {
            float4 w4 = ((const float4*)W)[(size_t)(kb + kk) * 32 + cg];
            #pragma unroll
            for (int i = 0; i < 4; ++i) {
                float a = (kk == 0) ? a4[i].x : (kk == 1) ? a4[i].y : (kk == 2) ? a4[i].z : a4[i].w;
                acc[i][0] = fmaf(a, w4.x, acc[i][0]);
                acc[i][1] = fmaf(a, w4.y, acc[i][1]);
                acc[i][2] = fmaf(a, w4.z, acc[i][2]);
                acc[i][3] = fmaf(a, w4.w, acc[i][3]);
            }
        }
    }
    float4 b4 = ((const float4*)bias)[cg];
    float gate = 0.f;
    if (mode == 1) gate = 1.f / (1.f + expf(-skipv[0]));
    #pragma unroll
    for (int i = 0; i < 4; ++i) {
        int rr = row0 + rg * 4 + i;
        if (rr < M) {
            size_t ci = (size_t)rr * 32 + cg;
            float4 o;
            o.x = acc[i][0] + b4.x; o.y = acc[i][1] + b4.y;
            o.z = acc[i][2] + b4.z; o.w = acc[i][3] + b4.w;
            if (mode == 1) {
                float4 hold = ((const float4*)C)[ci];
                o.x = gate * o.x + (1.f - gate) * hold.x;
                o.y = gate * o.y + (1.f - gate) * hold.y;
                o.z = gate * o.z + (1.f - gate) * hold.z;
                o.w = gate * o.w + (1.f - gate) * hold.w;
            }
            ((float4*)C)[ci] = o;
        }
    }
}

// ---------------- BatchNorm (training-mode batch stats, biased var) ----------------
__global__ __launch_bounds__(128) void bn_stats_kernel(const float* __restrict__ h,
                                                       float* __restrict__ stats, int n)
{
    int c = threadIdx.x;
    int r0 = blockIdx.x * 128;
    int r1 = min(r0 + 128, n);
    float s = 0.f, s2 = 0.f;
    for (int r = r0; r < r1; ++r) {
        float v = h[(size_t)r * 128 + c];
        s += v; s2 += v * v;
    }
    atomicAdd(&stats[c], s);
    atomicAdd(&stats[128 + c], s2);
}

__global__ __launch_bounds__(256) void bn_apply_kernel(float* __restrict__ h,
    const float* __restrict__ stats, const float* __restrict__ gamma,
    const float* __restrict__ beta, int n)
{
    int i = blockIdx.x * 256 + threadIdx.x;      // float4 index
    if (i >= n * 32) return;
    int c4 = i & 31;
    float invN = 1.f / (float)n;
    float4 v = ((const float4*)h)[i];
    float o[4] = {v.x, v.y, v.z, v.w};
    #pragma unroll
    for (int j = 0; j < 4; ++j) {
        int c = c4 * 4 + j;
        float mu = stats[c] * invN;
        float var = stats[128 + c] * invN - mu * mu;
        o[j] = (o[j] - mu) * rsqrtf(var + 1e-5f) * gamma[c] + beta[c];
    }
    ((float4*)h)[i] = make_float4(o[0], o[1], o[2], o[3]);
}

// ---------------- q_rel[n,r,h,d] = sum_e q[n,h,e] * a_rel[r,h,d,e] ----------------
__global__ __launch_bounds__(128) void qrel_kernel(const float* __restrict__ q,
    const float* __restrict__ arel, float* __restrict__ qrel, int n)
{
    const int t = threadIdx.x;
    const int r = t >> 5, hh = (t >> 3) & 3, dg = t & 7;
    float4 a4[4][8];                 // a_rel[r][hh][dg*4+j][e], e-contiguous
    const float4* ar4 = (const float4*)arel;
    #pragma unroll
    for (int j = 0; j < 4; ++j) {
        int d = dg * 4 + j;
        #pragma unroll
        for (int ec = 0; ec < 8; ++ec)
            a4[j][ec] = ar4[(size_t)((r * 4 + hh) * 32 + d) * 8 + ec];
    }
    for (int node = blockIdx.x; node < n; node += gridDim.x) {
        const float4* q4 = (const float4*)(q + (size_t)node * 128 + hh * 32);
        float acc0 = 0.f, acc1 = 0.f, acc2 = 0.f, acc3 = 0.f;
        #pragma unroll
        for (int ec = 0; ec < 8; ++ec) {
            float4 qv = q4[ec];
            acc0 += qv.x*a4[0][ec].x + qv.y*a4[0][ec].y + qv.z*a4[0][ec].z + qv.w*a4[0][ec].w;
            acc1 += qv.x*a4[1][ec].x + qv.y*a4[1][ec].y + qv.z*a4[1][ec].z + qv.w*a4[1][ec].w;
            acc2 += qv.x*a4[2][ec].x + qv.y*a4[2][ec].y + qv.z*a4[2][ec].z + qv.w*a4[2][ec].w;
            acc3 += qv.x*a4[3][ec].x + qv.y*a4[3][ec].y + qv.z*a4[3][ec].z + qv.w*a4[3][ec].w;
        }
        ((float4*)qrel)[(size_t)(node * 4 + r) * 32 + hh * 8 + dg] =
            make_float4(acc0, acc1, acc2, acc3);
    }
}

// ---------------- CSR build ----------------
__global__ __launch_bounds__(256) void zero_int_kernel(int* __restrict__ p, int n)
{
    int i = blockIdx.x * 256 + threadIdx.x;
    if (i < n) p[i] = 0;
}

__global__ __launch_bounds__(256) void hist_kernel(const int* __restrict__ ei,
                                                   int* __restrict__ cnt, int E)
{
    int e = blockIdx.x * 256 + threadIdx.x;
    if (e < E) atomicAdd(&cnt[ei[E + e]], 1);
}

__global__ __launch_bounds__(256) void scan_block_kernel(const int* __restrict__ cnt,
    int* __restrict__ excl, int* __restrict__ bsum, int n)
{
    __shared__ int tmp[256];
    int i = blockIdx.x * 256 + threadIdx.x;
    int v = (i < n) ? cnt[i] : 0;
    tmp[threadIdx.x] = v;
    __syncthreads();
    for (int ofs = 1; ofs < 256; ofs <<= 1) {
        int t = (threadIdx.x >= ofs) ? tmp[threadIdx.x - ofs] : 0;
        __syncthreads();
        tmp[threadIdx.x] += t;
        __syncthreads();
    }
    if (i < n) excl[i] = tmp[threadIdx.x] - v;
    if (threadIdx.x == 255) bsum[blockIdx.x] = tmp[255];
}

__global__ __launch_bounds__(256) void scan_bsum_kernel(int* __restrict__ bsum, int nb)
{
    __shared__ int tmp[256];
    int v = (threadIdx.x < nb) ? bsum[threadIdx.x] : 0;
    tmp[threadIdx.x] = v;
    __syncthreads();
    for (int ofs = 1; ofs < 256; ofs <<= 1) {
        int t = (threadIdx.x >= ofs) ? tmp[threadIdx.x - ofs] : 0;
        __syncthreads();
        tmp[threadIdx.x] += t;
        __syncthreads();
    }
    if (threadIdx.x < nb) bsum[threadIdx.x] = tmp[threadIdx.x] - v;
}

__global__ __launch_bounds__(256) void scan_add_kernel(int* __restrict__ excl,
    const int* __restrict__ bsum, int* __restrict__ fill, int n, int total)
{
    int i = blockIdx.x * 256 + threadIdx.x;
    if (i < n) {
        int o = excl[i] + bsum[blockIdx.x];
        excl[i] = o;
        fill[i] = o;
    }
    if (blockIdx.x == 0 && threadIdx.x == 0) excl[n] = total;
}

__global__ __launch_bounds__(256) void scatter_kernel(const int* __restrict__ ei,
    const int* __restrict__ et, int* __restrict__ fill, int* __restrict__ pack, int E)
{
    int e = blockIdx.x * 256 + threadIdx.x;
    if (e >= E) return;
    int dst = ei[E + e];
    int p = atomicAdd(&fill[dst], 1);
    pack[p] = ei[e] | (et[e] << 20);   // src in bits 0..19, rel in bits 20+
}

// ---------------- fused per-dst attention: score, segment softmax, weighted-V ----------------
// One wave per dst node. Lane owns elements [2*lane, 2*lane+1] of the 128-wide (h,d)
// flattening (h = lane>>4). Reads q_rel rows of its own node, writes agg to the SAME
// rows -> qa buffer is safely aliased (read into regs at start, written at end).
__global__ __launch_bounds__(256) void agg_fused_kernel(
    float* __restrict__ qa,
    const float* __restrict__ k, const float* __restrict__ v,
    const int* __restrict__ off, const int* __restrict__ pack,
    const float* __restrict__ prel, int n)
{
    __shared__ float sscore[4][DEGCAP * 4];
    const int wv = threadIdx.x >> 6;
    const int lane = threadIdx.x & 63;
    const int node = blockIdx.x * 4 + wv;
    const int h = lane >> 4;
    const bool valid = node < n;
    int beg = 0, end = 0;
    if (valid) {
        beg = __builtin_amdgcn_readfirstlane(off[node]);
        end = __builtin_amdgcn_readfirstlane(off[node + 1]);
    }
    const bool useLds = (end - beg) <= DEGCAP;

    float2 qr0 = {0,0}, qr1 = {0,0}, qr2 = {0,0}, qr3 = {0,0};
    float pr0 = 0, pr1 = 0, pr2 = 0, pr3 = 0;
    if (valid) {
        const float2* qp = (const float2*)(qa + (size_t)node * 512);
        qr0 = qp[lane]; qr1 = qp[64 + lane]; qr2 = qp[128 + lane]; qr3 = qp[192 + lane];
        const float sc = 0.17677669529663687f;   // 1/sqrt(32)
        pr0 = prel[h] * sc; pr1 = prel[4 + h] * sc;
        pr2 = prel[8 + h] * sc; pr3 = prel[12 + h] * sc;
    }

    float m0 = -3.4e38f, m1 = -3.4e38f, m2 = -3.4e38f, m3 = -3.4e38f;
    for (int p = beg; p < end; ++p) {
        int pk = __builtin_amdgcn_readfirstlane(pack[p]);
        int src = pk & 0xFFFFF, r = pk >> 20;
        float2 k2 = *(const float2*)(k + (size_t)src * 128 + lane * 2);
        float qx, qy, pr;
        if (r == 0)      { qx = qr0.x; qy = qr0.y; pr = pr0; }
        else if (r == 1) { qx = qr1.x; qy = qr1.y; pr = pr1; }
        else if (r == 2) { qx = qr2.x; qy = qr2.y; pr = pr2; }
        else             { qx = qr3.x; qy = qr3.y; pr = pr3; }
        float part = qx * k2.x + qy * k2.y;
        part += __shfl_xor(part, 1); part += __shfl_xor(part, 2);
        part += __shfl_xor(part, 4); part += __shfl_xor(part, 8);
        float s = part * pr;
        if (useLds && (lane & 15) == 0) sscore[wv][(p - beg) * 4 + h] = s;
        if (r == 0)      m0 = fmaxf(m0, s);
        else if (r == 1) m1 = fmaxf(m1, s);
        else if (r == 2) m2 = fmaxf(m2, s);
        else             m3 = fmaxf(m3, s);
    }
    __syncthreads();   // all threads reach (loops skipped for empty ranges)

    float2 a0 = {0,0}, a1 = {0,0}, a2 = {0,0}, a3 = {0,0};
    float s0 = 0, s1 = 0, s2 = 0, s3 = 0;
    for (int p = beg; p < end; ++p) {
        int pk = __builtin_amdgcn_readfirstlane(pack[p]);
        int src = pk & 0xFFFFF, r = pk >> 20;
        float2 v2 = *(const float2*)(v + (size_t)src * 128 + lane * 2);
        float s;
        if (useLds) {
            s = sscore[wv][(p - beg) * 4 + h];
        } else {   // rare giant-degree fallback: recompute the score
            float2 k2 = *(const float2*)(k + (size_t)src * 128 + lane * 2);
            float qx, qy, pr;
            if (r == 0)      { qx = qr0.x; qy = qr0.y; pr = pr0; }
            else if (r == 1) { qx = qr1.x; qy = qr1.y; pr = pr1; }
            else if (r == 2) { qx = qr2.x; qy = qr2.y; pr = pr2; }
            else             { qx = qr3.x; qy = qr3.y; pr = pr3; }
            float part = qx * k2.x + qy * k2.y;
            part += __shfl_xor(part, 1); part += __shfl_xor(part, 2);
            part += __shfl_xor(part, 4); part += __shfl_xor(part, 8);
            s = part * pr;
        }
        float mm = (r == 0) ? m0 : (r == 1) ? m1 : (r == 2) ? m2 : m3;
        float e = __expf(s - mm);
        if (r == 0)      { s0 += e; a0.x += e * v2.x; a0.y += e * v2.y; }
        else if (r == 1) { s1 += e; a1.x += e * v2.x; a1.y += e * v2.y; }
        else if (r == 2) { s2 += e; a2.x += e * v2.x; a2.y += e * v2.y; }
        else             { s3 += e; a3.x += e * v2.x; a3.y += e * v2.y; }
    }

    if (valid) {
        float2* op = (float2*)(qa + (size_t)node * 512);
        float i0 = s0 > 0.f ? 1.f / s0 : 0.f;
        float i1 = s1 > 0.f ? 1.f / s1 : 0.f;
        float i2 = s2 > 0.f ? 1.f / s2 : 0.f;
        float i3 = s3 > 0.f ? 1.f / s3 : 0.f;
        op[lane]       = make_float2(a0.x * i0, a0.y * i0);
        op[64 + lane]  = make_float2(a1.x * i1, a1.y * i1);
        op[128 + lane] = make_float2(a2.x * i2, a2.y * i2);
        op[192 + lane] = make_float2(a3.x * i3, a3.y * i3);
    }
}

// ---------------- msg[n,h,e] = gelu( sum_{r,d} agg[n,r,h,d] * m_rel[r,h,d,e] ) ----------------
__global__ __launch_bounds__(128) void msg_kernel(const float* __restrict__ agg,
    const float* __restrict__ mrel, float* __restrict__ msg, int n)
{
    const int t = threadIdx.x;
    const int hh = t >> 5, r = (t >> 3) & 3, eg = t & 7;   // r in shuffle-reachable bits 3..4
    float4 m4[32];                    // m_rel[r][hh][d][eg*4..+3]
    const float4* mr4 = (const float4*)mrel;
    #pragma unroll
    for (int d = 0; d < 32; ++d)
        m4[d] = mr4[(size_t)((r * 4 + hh) * 32 + d) * 8 + eg];
    for (int node = blockIdx.x; node < n; node += gridDim.x) {
        const float4* ag4 = (const float4*)(agg + (size_t)(node * 4 + r) * 128 + hh * 32);
        float4 acc = make_float4(0.f, 0.f, 0.f, 0.f);
        #pragma unroll
        for (int dc = 0; dc < 8; ++dc) {
            float4 av = ag4[dc];
            acc.x += av.x*m4[dc*4+0].x + av.y*m4[dc*4+1].x + av.z*m4[dc*4+2].x + av.w*m4[dc*4+3].x;
            acc.y += av.x*m4[dc*4+0].y + av.y*m4[dc*4+1].y + av.z*m4[dc*4+2].y + av.w*m4[dc*4+3].y;
            acc.z += av.x*m4[dc*4+0].z + av.y*m4[dc*4+1].z + av.z*m4[dc*4+2].z + av.w*m4[dc*4+3].z;
            acc.w += av.x*m4[dc*4+0].w + av.y*m4[dc*4+1].w + av.z*m4[dc*4+2].w + av.w*m4[dc*4+3].w;
        }
        // reduce over r (lanes differing in bits 3,4 of lane id)
        acc.x += __shfl_xor(acc.x, 8);  acc.x += __shfl_xor(acc.x, 16);
        acc.y += __shfl_xor(acc.y, 8);  acc.y += __shfl_xor(acc.y, 16);
        acc.z += __shfl_xor(acc.z, 8);  acc.z += __shfl_xor(acc.z, 16);
        acc.w += __shfl_xor(acc.w, 8);  acc.w += __shfl_xor(acc.w, 16);
        if (r == 0) {
            float4 o;
            o.x = 0.5f * acc.x * (1.f + erff(acc.x * 0.70710678118654752f));
            o.y = 0.5f * acc.y * (1.f + erff(acc.y * 0.70710678118654752f));
            o.z = 0.5f * acc.z * (1.f + erff(acc.z * 0.70710678118654752f));
            o.w = 0.5f * acc.w * (1.f + erff(acc.w * 0.70710678118654752f));
            ((float4*)msg)[(size_t)node * 32 + hh * 8 + eg] = o;
        }
    }
}

// ---------------- final gather h[idx] ----------------
__global__ __launch_bounds__(256) void gather_kernel(const float* __restrict__ h,
    const int* __restrict__ idx, float* __restrict__ out, int m)
{
    int i = blockIdx.x * 256 + threadIdx.x;   // m*32 float4s
    if (i >= m * 32) return;
    int row = i >> 5, c4 = i & 31;
    ((float4*)out)[i] = ((const float4*)(h + (size_t)idx[row] * 128))[c4];
}

extern "C" void kernel_launch(void* const* d_in, const int* in_sizes, int n_in,
                              void* d_out, int out_size, void* d_ws, size_t ws_size,
                              hipStream_t stream)
{
    const float* x      = (const float*)d_in[0];
    const float* proj_w = (const float*)d_in[1];
    const float* proj_b = (const float*)d_in[2];
    const float* bn_g   = (const float*)d_in[3];
    const float* bn_b   = (const float*)d_in[4];
    const float* q_w    = (const float*)d_in[5];
    const float* q_b    = (const float*)d_in[6];
    const float* k_w    = (const float*)d_in[7];
    const float* k_b    = (const float*)d_in[8];
    const float* v_w    = (const float*)d_in[9];
    const float* v_b    = (const float*)d_in[10];
    const float* a_w    = (const float*)d_in[11];
    const float* a_b    = (const float*)d_in[12];
    const float* skip   = (const float*)d_in[13];
    const float* a_rel  = (const float*)d_in[14];
    const float* m_rel  = (const float*)d_in[15];
    const float* p_rel  = (const float*)d_in[16];
    const int* edge_index = (const int*)d_in[17];
    const int* edge_type  = (const int*)d_in[18];
    const int* idx        = (const int*)d_in[19];
    float* out = (float*)d_out;

    const int N = NN, E = EE;
    float* ws = (float*)d_ws;
    size_t o = 0;
    float* h  = ws + o;  o += (size_t)N * 128;
    float* q  = ws + o;  o += (size_t)N * 128;
    float* k  = ws + o;  o += (size_t)N * 128;
    float* v  = ws + o;  o += (size_t)N * 128;
    float* B1 = ws + o;  o += (size_t)N * 512;        // q_rel, overwritten in place by agg
    float* msg = ws + o;   o += (size_t)N * 128;
    float* stats = ws + o; o += 256;
    int* cnt  = (int*)(ws + o); o += N;
    int* off  = (int*)(ws + o); o += N + 1;
    int* fill = (int*)(ws + o); o += N;
    int* bsum = (int*)(ws + o); o += 256;
    int* pack = (int*)(ws + o); o += E;

    const int mmGrid = (N + 31) / 32;
    const int NB = (N + 255) / 256;

    // ---- CSR build (edges constant across layers) ----
    zero_int_kernel<<<NB, 256, 0, stream>>>(cnt, N);
    hist_kernel<<<(E + 255) / 256, 256, 0, stream>>>(edge_index, cnt, E);
    scan_block_kernel<<<NB, 256, 0, stream>>>(cnt, off, bsum, N);
    scan_bsum_kernel<<<1, 256, 0, stream>>>(bsum, NB);
    scan_add_kernel<<<NB, 256, 0, stream>>>(off, bsum, fill, N, E);
    scatter_kernel<<<(E + 255) / 256, 256, 0, stream>>>(edge_index, edge_type, fill, pack, E);

    // ---- proj + BN ----
    matmul128<<<mmGrid, 256, 0, stream>>>(x, proj_w, proj_b, h, N, 0, nullptr);
    zero_int_kernel<<<1, 256, 0, stream>>>((int*)stats, 256);
    bn_stats_kernel<<<(N + 127) / 128, 128, 0, stream>>>(h, stats, N);
    bn_apply_kernel<<<(N * 32 + 255) / 256, 256, 0, stream>>>(h, stats, bn_g, bn_b, N);

    for (int l = 0; l < 2; ++l) {
        const float* qwl = q_w + (size_t)l * 16384;
        const float* kwl = k_w + (size_t)l * 16384;
        const float* vwl = v_w + (size_t)l * 16384;
        const float* awl = a_w + (size_t)l * 16384;
        const float* arl = a_rel + (size_t)l * 16384;
        const float* mrl = m_rel + (size_t)l * 16384;

        matmul128<<<mmGrid, 256, 0, stream>>>(h, qwl, q_b + l * 128, q, N, 0, nullptr);
        matmul128<<<mmGrid, 256, 0, stream>>>(h, kwl, k_b + l * 128, k, N, 0, nullptr);
        matmul128<<<mmGrid, 256, 0, stream>>>(h, vwl, v_b + l * 128, v, N, 0, nullptr);

        qrel_kernel<<<2048, 128, 0, stream>>>(q, arl, B1, N);
        agg_fused_kernel<<<(N + 3) / 4, 256, 0, stream>>>(B1, k, v, off, pack,
                                                          p_rel + l * 16, N);
        msg_kernel<<<2048, 128, 0, stream>>>(B1, mrl, msg, N);
        matmul128<<<mmGrid, 256, 0, stream>>>(msg, awl, a_b + l * 128, h, N, 1, skip + l);
    }

    gather_kernel<<<(MOUT * 32 + 255) / 256, 256, 0, stream>>>(h, idx, out, MOUT);
}

// Round 3
// 756.813 us; speedup vs baseline: 4.0297x; 1.4878x over previous
//
#include <hip/hip_runtime.h>
#include <math.h>

#define NN 50000
#define EE 600000
#define MOUT 10000
#define DEGCAP 96

typedef short bf16x8 __attribute__((ext_vector_type(8)));
typedef float f32x4 __attribute__((ext_vector_type(4)));

__device__ __forceinline__ unsigned short f2bf(float x) {
    unsigned int u = __float_as_uint(x);
    u = (u + 0x7FFFu + ((u >> 16) & 1u)) >> 16;
    return (unsigned short)u;
}
__device__ __forceinline__ float bf2f(unsigned int b) {
    return __uint_as_float(b << 16);
}

// ============ bf16 MFMA GEMM: C[M,NC] = epilogue(A[M,K] @ Wt[NC,K]^T + bias) ============
// A row-major [M][K] bf16 (K contiguous); Wt row-major [NC][K] bf16 (pre-transposed weight).
// mode 0: Cf = val (fp32)        mode 3: Cb = bf16(val)
// mode 2: Cb = bf16(gelu(val))   mode 1: nv = g*val+(1-g)*Cf; Cf=nv; Cb=bf16(nv)
__global__ __launch_bounds__(256) void gemm_bf16(
    const unsigned short* __restrict__ A, const unsigned short* __restrict__ Wt,
    const float* __restrict__ bias, float* __restrict__ Cf,
    unsigned short* __restrict__ Cb, int M, int K, int NC, int mode,
    const float* __restrict__ skipv)
{
    __shared__ unsigned short As[128 * 40];   // 32-k tiles padded to 40 (bank spread)
    __shared__ unsigned short Bs[128 * 40];
    const int t = threadIdx.x;
    const int wave = t >> 6, lane = t & 63;
    const int quad = lane >> 4, l16 = lane & 15;
    const int row0 = blockIdx.x * 128, col0 = blockIdx.y * 128;
    const int wr = (wave & 1) * 64, wc = (wave >> 1) * 64;
    const int sr = t >> 1, sc = (t & 1) * 16;

    f32x4 acc[4][4];
    #pragma unroll
    for (int i = 0; i < 4; ++i)
        #pragma unroll
        for (int j = 0; j < 4; ++j)
            acc[i][j] = (f32x4){0.f, 0.f, 0.f, 0.f};

    for (int kb = 0; kb < K; kb += 32) {
        uint4 av0 = make_uint4(0, 0, 0, 0), av1 = av0;
        int grow = row0 + sr;
        if (grow < M) {
            const uint4* ap = (const uint4*)(A + (size_t)grow * K + kb + sc);
            av0 = ap[0]; av1 = ap[1];
        }
        const uint4* bp = (const uint4*)(Wt + (size_t)(col0 + sr) * K + kb + sc);
        uint4 bv0 = bp[0], bv1 = bp[1];
        __syncthreads();
        *(uint4*)(As + sr * 40 + sc)     = av0;
        *(uint4*)(As + sr * 40 + sc + 8) = av1;
        *(uint4*)(Bs + sr * 40 + sc)     = bv0;
        *(uint4*)(Bs + sr * 40 + sc + 8) = bv1;
        __syncthreads();
        bf16x8 af[4], bfr[4];
        #pragma unroll
        for (int f = 0; f < 4; ++f) {
            af[f]  = *(const bf16x8*)(As + (wr + f * 16 + l16) * 40 + quad * 8);
            bfr[f] = *(const bf16x8*)(Bs + (wc + f * 16 + l16) * 40 + quad * 8);
        }
        #pragma unroll
        for (int fr = 0; fr < 4; ++fr)
            #pragma unroll
            for (int fc = 0; fc < 4; ++fc)
                acc[fr][fc] = __builtin_amdgcn_mfma_f32_16x16x32_bf16(
                    af[fr], bfr[fc], acc[fr][fc], 0, 0, 0);
    }

    float gate = 0.f;
    if (mode == 1) gate = 1.f / (1.f + __expf(-skipv[0]));
    float b4[4];
    #pragma unroll
    for (int fc = 0; fc < 4; ++fc)
        b4[fc] = bias ? bias[col0 + wc + fc * 16 + l16] : 0.f;
    #pragma unroll
    for (int fr = 0; fr < 4; ++fr) {
        #pragma unroll
        for (int reg = 0; reg < 4; ++reg) {
            int row = row0 + wr + fr * 16 + quad * 4 + reg;
            if (row >= M) continue;
            #pragma unroll
            for (int fc = 0; fc < 4; ++fc) {
                int col = col0 + wc + fc * 16 + l16;
                size_t ci = (size_t)row * NC + col;
                float val = acc[fr][fc][reg] + b4[fc];
                if (mode == 0) {
                    Cf[ci] = val;
                } else if (mode == 3) {
                    Cb[ci] = f2bf(val);
                } else if (mode == 2) {
                    float gl = 0.5f * val * (1.f + erff(val * 0.70710678118654752f));
                    Cb[ci] = f2bf(gl);
                } else {
                    float nv = gate * val + (1.f - gate) * Cf[ci];
                    Cf[ci] = nv;
                    Cb[ci] = f2bf(nv);
                }
            }
        }
    }
}

// ============ weight prep ============
// 7 plain 128x128 transposed casts: proj, k0, v0, a0, k1, v1, a1
__global__ __launch_bounds__(256) void cast_transpose_all(
    const float* __restrict__ proj_w, const float* __restrict__ k_w,
    const float* __restrict__ v_w, const float* __restrict__ a_w,
    unsigned short* __restrict__ wt_all)
{
    int wi = blockIdx.x >> 6;
    int flat = (blockIdx.x & 63) * 256 + threadIdx.x;
    int n = flat >> 7, c = flat & 127;
    const float* src;
    switch (wi) {
        case 0: src = proj_w; break;
        case 1: src = k_w; break;
        case 2: src = v_w; break;
        case 3: src = a_w; break;
        case 4: src = k_w + 16384; break;
        case 5: src = v_w + 16384; break;
        default: src = a_w + 16384; break;
    }
    wt_all[(size_t)wi * 16384 + n * 128 + c] = f2bf(src[c * 128 + n]);
}

// W_qrel_t[(r,h,d)][c] = sum_e q_w[c][h*32+e] * a_rel[r,h,d,e];  bias[(r,h,d)] likewise from q_b
__global__ __launch_bounds__(256) void qrel_weight_kernel(
    const float* __restrict__ q_w, const float* __restrict__ q_b,
    const float* __restrict__ a_rel, unsigned short* __restrict__ qrel_wt,
    float* __restrict__ qrel_bias)
{
    int l = blockIdx.y;
    int flat = blockIdx.x * 256 + threadIdx.x;
    int n = flat >> 7, c = flat & 127;
    int r = n >> 7, h = (n >> 5) & 3, d = n & 31;
    const float* qwc = q_w + (size_t)l * 16384 + c * 128 + h * 32;
    const float* ar  = a_rel + (size_t)(l * 4 + r) * 4096 + h * 1024 + d * 32;
    float s = 0.f;
    #pragma unroll 8
    for (int e = 0; e < 32; ++e) s += qwc[e] * ar[e];
    qrel_wt[(size_t)l * 65536 + (size_t)n * 128 + c] = f2bf(s);
    if (c == 0) {
        const float* qb = q_b + l * 128 + h * 32;
        float b = 0.f;
        #pragma unroll 8
        for (int e = 0; e < 32; ++e) b += qb[e] * ar[e];
        qrel_bias[l * 512 + n] = b;
    }
}

// W_msg_t[(h,e)][(r,h2,d)] = (h2==h) ? m_rel[r,h,d,e] : 0   (128 x 512 bf16)
__global__ __launch_bounds__(256) void msg_weight_kernel(
    const float* __restrict__ m_rel, unsigned short* __restrict__ msg_wt)
{
    int l = blockIdx.y;
    int flat = blockIdx.x * 256 + threadIdx.x;
    int n = flat >> 9, kk = flat & 511;
    int h = n >> 5, e = n & 31;
    int r = kk >> 7, h2 = (kk >> 5) & 3, d = kk & 31;
    float val = (h2 == h) ? m_rel[(size_t)(l * 4 + r) * 4096 + h * 1024 + d * 32 + e] : 0.f;
    msg_wt[(size_t)l * 65536 + (size_t)n * 512 + kk] = f2bf(val);
}

__global__ __launch_bounds__(256) void cast_x_kernel(const float* __restrict__ x,
    unsigned short* __restrict__ xb, int n)
{
    int i = blockIdx.x * 256 + threadIdx.x;   // float4 index
    if (i >= n * 32) return;
    float4 v = ((const float4*)x)[i];
    uint2 pk;
    pk.x = (unsigned int)f2bf(v.x) | ((unsigned int)f2bf(v.y) << 16);
    pk.y = (unsigned int)f2bf(v.z) | ((unsigned int)f2bf(v.w) << 16);
    ((uint2*)xb)[i] = pk;
}

// ============ BatchNorm ============
__global__ __launch_bounds__(128) void bn_stats_kernel(const float* __restrict__ h,
                                                       float* __restrict__ stats, int n)
{
    int c = threadIdx.x;
    int r0 = blockIdx.x * 128;
    int r1 = min(r0 + 128, n);
    float s = 0.f, s2 = 0.f;
    for (int r = r0; r < r1; ++r) {
        float v = h[(size_t)r * 128 + c];
        s += v; s2 += v * v;
    }
    atomicAdd(&stats[c], s);
    atomicAdd(&stats[128 + c], s2);
}

__global__ __launch_bounds__(256) void bn_apply_kernel(float* __restrict__ h,
    unsigned short* __restrict__ hbf, const float* __restrict__ stats,
    const float* __restrict__ gamma, const float* __restrict__ beta, int n)
{
    int i = blockIdx.x * 256 + threadIdx.x;      // float4 index
    if (i >= n * 32) return;
    int c4 = i & 31;
    float invN = 1.f / (float)n;
    float4 v = ((const float4*)h)[i];
    float o[4] = {v.x, v.y, v.z, v.w};
    #pragma unroll
    for (int j = 0; j < 4; ++j) {
        int c = c4 * 4 + j;
        float mu = stats[c] * invN;
        float var = stats[128 + c] * invN - mu * mu;
        o[j] = (o[j] - mu) * rsqrtf(var + 1e-5f) * gamma[c] + beta[c];
    }
    ((float4*)h)[i] = make_float4(o[0], o[1], o[2], o[3]);
    uint2 pk;
    pk.x = (unsigned int)f2bf(o[0]) | ((unsigned int)f2bf(o[1]) << 16);
    pk.y = (unsigned int)f2bf(o[2]) | ((unsigned int)f2bf(o[3]) << 16);
    ((uint2*)hbf)[i] = pk;
}

// ============ CSR build ============
__global__ __launch_bounds__(256) void zero_int_kernel(int* __restrict__ p, int n)
{
    int i = blockIdx.x * 256 + threadIdx.x;
    if (i < n) p[i] = 0;
}

__global__ __launch_bounds__(256) void hist_kernel(const int* __restrict__ ei,
                                                   int* __restrict__ cnt, int E)
{
    int e = blockIdx.x * 256 + threadIdx.x;
    if (e < E) atomicAdd(&cnt[ei[E + e]], 1);
}

__global__ __launch_bounds__(256) void scan_block_kernel(const int* __restrict__ cnt,
    int* __restrict__ excl, int* __restrict__ bsum, int n)
{
    __shared__ int tmp[256];
    int i = blockIdx.x * 256 + threadIdx.x;
    int v = (i < n) ? cnt[i] : 0;
    tmp[threadIdx.x] = v;
    __syncthreads();
    for (int ofs = 1; ofs < 256; ofs <<= 1) {
        int t = (threadIdx.x >= ofs) ? tmp[threadIdx.x - ofs] : 0;
        __syncthreads();
        tmp[threadIdx.x] += t;
        __syncthreads();
    }
    if (i < n) excl[i] = tmp[threadIdx.x] - v;
    if (threadIdx.x == 255) bsum[blockIdx.x] = tmp[255];
}

__global__ __launch_bounds__(256) void scan_bsum_kernel(int* __restrict__ bsum, int nb)
{
    __shared__ int tmp[256];
    int v = (threadIdx.x < nb) ? bsum[threadIdx.x] : 0;
    tmp[threadIdx.x] = v;
    __syncthreads();
    for (int ofs = 1; ofs < 256; ofs <<= 1) {
        int t = (threadIdx.x >= ofs) ? tmp[threadIdx.x - ofs] : 0;
        __syncthreads();
        tmp[threadIdx.x] += t;
        __syncthreads();
    }
    if (threadIdx.x < nb) bsum[threadIdx.x] = tmp[threadIdx.x] - v;
}

__global__ __launch_bounds__(256) void scan_add_kernel(int* __restrict__ excl,
    const int* __restrict__ bsum, int* __restrict__ fill, int n, int total)
{
    int i = blockIdx.x * 256 + threadIdx.x;
    if (i < n) {
        int o = excl[i] + bsum[blockIdx.x];
        excl[i] = o;
        fill[i] = o;
    }
    if (blockIdx.x == 0 && threadIdx.x == 0) excl[n] = total;
}

__global__ __launch_bounds__(256) void scatter_kernel(const int* __restrict__ ei,
    const int* __restrict__ et, int* __restrict__ fill, int* __restrict__ pack, int E)
{
    int e = blockIdx.x * 256 + threadIdx.x;
    if (e >= E) return;
    int dst = ei[E + e];
    int p = atomicAdd(&fill[dst], 1);
    pack[p] = ei[e] | (et[e] << 20);   // src in bits 0..19, rel in bits 20+
}

// ============ fused per-dst attention (bf16 gathers, LDS pack, 4x unroll) ============
__global__ __launch_bounds__(256) void agg_fused_kernel(
    const unsigned short* __restrict__ qrel, const unsigned short* __restrict__ kbf,
    const unsigned short* __restrict__ vbf,
    const int* __restrict__ off, const int* __restrict__ pack,
    const float* __restrict__ prel, unsigned short* __restrict__ aggb, int n)
{
    __shared__ float sscore[4][DEGCAP * 4];
    __shared__ int   spack[4][DEGCAP];
    const int wv = threadIdx.x >> 6;
    const int lane = threadIdx.x & 63;
    const int node = blockIdx.x * 4 + wv;
    const int h = lane >> 4;
    const bool valid = node < n;
    int beg = 0, end = 0;
    if (valid) {
        beg = __builtin_amdgcn_readfirstlane(off[node]);
        end = __builtin_amdgcn_readfirstlane(off[node + 1]);
    }
    const int deg = end - beg;
    const bool useLds = deg <= DEGCAP;

    float2 qr0 = {0,0}, qr1 = {0,0}, qr2 = {0,0}, qr3 = {0,0};
    float pr0 = 0, pr1 = 0, pr2 = 0, pr3 = 0;
    if (valid) {
        const unsigned int* qp = (const unsigned int*)(qrel + (size_t)node * 512);
        unsigned int u0 = qp[lane], u1 = qp[64 + lane], u2 = qp[128 + lane], u3 = qp[192 + lane];
        qr0.x = bf2f(u0 & 0xFFFFu); qr0.y = bf2f(u0 >> 16);
        qr1.x = bf2f(u1 & 0xFFFFu); qr1.y = bf2f(u1 >> 16);
        qr2.x = bf2f(u2 & 0xFFFFu); qr2.y = bf2f(u2 >> 16);
        qr3.x = bf2f(u3 & 0xFFFFu); qr3.y = bf2f(u3 >> 16);
        const float sc = 0.17677669529663687f;
        pr0 = prel[h] * sc; pr1 = prel[4 + h] * sc;
        pr2 = prel[8 + h] * sc; pr3 = prel[12 + h] * sc;
    }
    if (useLds) {
        for (int i = lane; i < deg; i += 64) spack[wv][i] = pack[beg + i];
        asm volatile("s_waitcnt lgkmcnt(0)" ::: "memory");
    }

    float m0 = -3.4e38f, m1 = -3.4e38f, m2 = -3.4e38f, m3 = -3.4e38f;
    if (useLds) {
        for (int p0 = 0; p0 < deg; p0 += 4) {
            int pk4[4]; float kx[4], ky[4];
            #pragma unroll
            for (int j = 0; j < 4; ++j) {
                int ii = p0 + j; if (ii >= deg) ii = deg - 1;
                pk4[j] = spack[wv][ii];
            }
            #pragma unroll
            for (int j = 0; j < 4; ++j) {
                int src = pk4[j] & 0xFFFFF;
                unsigned int u = *(const unsigned int*)(kbf + (size_t)src * 128 + lane * 2);
                kx[j] = bf2f(u & 0xFFFFu); ky[j] = bf2f(u >> 16);
            }
            #pragma unroll
            for (int j = 0; j < 4; ++j) {
                int ii = p0 + j; if (ii >= deg) ii = deg - 1;
                int r = pk4[j] >> 20;
                float qx = (r == 0) ? qr0.x : (r == 1) ? qr1.x : (r == 2) ? qr2.x : qr3.x;
                float qy = (r == 0) ? qr0.y : (r == 1) ? qr1.y : (r == 2) ? qr2.y : qr3.y;
                float pr = (r == 0) ? pr0 : (r == 1) ? pr1 : (r == 2) ? pr2 : pr3;
                float part = qx * kx[j] + qy * ky[j];
                part += __shfl_xor(part, 1); part += __shfl_xor(part, 2);
                part += __shfl_xor(part, 4); part += __shfl_xor(part, 8);
                float s = part * pr;
                if ((lane & 15) == 0) sscore[wv][ii * 4 + h] = s;
                if (r == 0)      m0 = fmaxf(m0, s);
                else if (r == 1) m1 = fmaxf(m1, s);
                else if (r == 2) m2 = fmaxf(m2, s);
                else             m3 = fmaxf(m3, s);
            }
        }
    } else {
        for (int p = beg; p < end; ++p) {
            int pk = __builtin_amdgcn_readfirstlane(pack[p]);
            int src = pk & 0xFFFFF, r = pk >> 20;
            unsigned int u = *(const unsigned int*)(kbf + (size_t)src * 128 + lane * 2);
            float kxx = bf2f(u & 0xFFFFu), kyy = bf2f(u >> 16);
            float qx = (r == 0) ? qr0.x : (r == 1) ? qr1.x : (r == 2) ? qr2.x : qr3.x;
            float qy = (r == 0) ? qr0.y : (r == 1) ? qr1.y : (r == 2) ? qr2.y : qr3.y;
            float pr = (r == 0) ? pr0 : (r == 1) ? pr1 : (r == 2) ? pr2 : pr3;
            float part = qx * kxx + qy * kyy;
            part += __shfl_xor(part, 1); part += __shfl_xor(part, 2);
            part += __shfl_xor(part, 4); part += __shfl_xor(part, 8);
            float s = part * pr;
            if (r == 0)      m0 = fmaxf(m0, s);
            else if (r == 1) m1 = fmaxf(m1, s);
            else if (r == 2) m2 = fmaxf(m2, s);
            else             m3 = fmaxf(m3, s);
        }
    }
    __syncthreads();

    float2 a0 = {0,0}, a1 = {0,0}, a2 = {0,0}, a3 = {0,0};
    float s0 = 0, s1 = 0, s2 = 0, s3 = 0;
    if (useLds) {
        for (int p0 = 0; p0 < deg; p0 += 4) {
            int pk4[4]; float vx[4], vy[4];
            #pragma unroll
            for (int j = 0; j < 4; ++j) {
                int ii = p0 + j; if (ii >= deg) ii = deg - 1;
                pk4[j] = spack[wv][ii];
            }
            #pragma unroll
            for (int j = 0; j < 4; ++j) {
                int src = pk4[j] & 0xFFFFF;
                unsigned int u = *(const unsigned int*)(vbf + (size_t)src * 128 + lane * 2);
                vx[j] = bf2f(u & 0xFFFFu); vy[j] = bf2f(u >> 16);
            }
            #pragma unroll
            for (int j = 0; j < 4; ++j) {
                if (p0 + j >= deg) break;
                int r = pk4[j] >> 20;
                float s = sscore[wv][(p0 + j) * 4 + h];
                float mm = (r == 0) ? m0 : (r == 1) ? m1 : (r == 2) ? m2 : m3;
                float e = __expf(s - mm);
                if (r == 0)      { s0 += e; a0.x += e * vx[j]; a0.y += e * vy[j]; }
                else if (r == 1) { s1 += e; a1.x += e * vx[j]; a1.y += e * vy[j]; }
                else if (r == 2) { s2 += e; a2.x += e * vx[j]; a2.y += e * vy[j]; }
                else             { s3 += e; a3.x += e * vx[j]; a3.y += e * vy[j]; }
            }
        }
    } else {
        for (int p = beg; p < end; ++p) {
            int pk = __builtin_amdgcn_readfirstlane(pack[p]);
            int src = pk & 0xFFFFF, r = pk >> 20;
            unsigned int uk = *(const unsigned int*)(kbf + (size_t)src * 128 + lane * 2);
            unsigned int uv = *(const unsigned int*)(vbf + (size_t)src * 128 + lane * 2);
            float kxx = bf2f(uk & 0xFFFFu), kyy = bf2f(uk >> 16);
            float vxx = bf2f(uv & 0xFFFFu), vyy = bf2f(uv >> 16);
            float qx = (r == 0) ? qr0.x : (r == 1) ? qr1.x : (r == 2) ? qr2.x : qr3.x;
            float qy = (r == 0) ? qr0.y : (r == 1) ? qr1.y : (r == 2) ? qr2.y : qr3.y;
            float pr = (r == 0) ? pr0 : (r == 1) ? pr1 : (r == 2) ? pr2 : pr3;
            float part = qx * kxx + qy * kyy;
            part += __shfl_xor(part, 1); part += __shfl_xor(part, 2);
            part += __shfl_xor(part, 4); part += __shfl_xor(part, 8);
            float s = part * pr;
            float mm = (r == 0) ? m0 : (r == 1) ? m1 : (r == 2) ? m2 : m3;
            float e = __expf(s - mm);
            if (r == 0)      { s0 += e; a0.x += e * vxx; a0.y += e * vyy; }
            else if (r == 1) { s1 += e; a1.x += e * vxx; a1.y += e * vyy; }
            else if (r == 2) { s2 += e; a2.x += e * vxx; a2.y += e * vyy; }
            else             { s3 += e; a3.x += e * vxx; a3.y += e * vyy; }
        }
    }

    if (valid) {
        unsigned int* op = (unsigned int*)(aggb + (size_t)node * 512);
        float i0 = s0 > 0.f ? 1.f / s0 : 0.f;
        float i1 = s1 > 0.f ? 1.f / s1 : 0.f;
        float i2 = s2 > 0.f ? 1.f / s2 : 0.f;
        float i3 = s3 > 0.f ? 1.f / s3 : 0.f;
        op[lane]       = (unsigned int)f2bf(a0.x * i0) | ((unsigned int)f2bf(a0.y * i0) << 16);
        op[64 + lane]  = (unsigned int)f2bf(a1.x * i1) | ((unsigned int)f2bf(a1.y * i1) << 16);
        op[128 + lane] = (unsigned int)f2bf(a2.x * i2) | ((unsigned int)f2bf(a2.y * i2) << 16);
        op[192 + lane] = (unsigned int)f2bf(a3.x * i3) | ((unsigned int)f2bf(a3.y * i3) << 16);
    }
}

// ============ final gather ============
__global__ __launch_bounds__(256) void gather_kernel(const float* __restrict__ h,
    const int* __restrict__ idx, float* __restrict__ out, int m)
{
    int i = blockIdx.x * 256 + threadIdx.x;   // m*32 float4s
    if (i >= m * 32) return;
    int row = i >> 5, c4 = i & 31;
    ((float4*)out)[i] = ((const float4*)(h + (size_t)idx[row] * 128))[c4];
}

extern "C" void kernel_launch(void* const* d_in, const int* in_sizes, int n_in,
                              void* d_out, int out_size, void* d_ws, size_t ws_size,
                              hipStream_t stream)
{
    const float* x      = (const float*)d_in[0];
    const float* proj_w = (const float*)d_in[1];
    const float* proj_b = (const float*)d_in[2];
    const float* bn_g   = (const float*)d_in[3];
    const float* bn_b   = (const float*)d_in[4];
    const float* q_w    = (const float*)d_in[5];
    const float* q_b    = (const float*)d_in[6];
    const float* k_w    = (const float*)d_in[7];
    const float* k_b    = (const float*)d_in[8];
    const float* v_w    = (const float*)d_in[9];
    const float* v_b    = (const float*)d_in[10];
    const float* a_w    = (const float*)d_in[11];
    const float* a_b    = (const float*)d_in[12];
    const float* skip   = (const float*)d_in[13];
    const float* a_rel  = (const float*)d_in[14];
    const float* m_rel  = (const float*)d_in[15];
    const float* p_rel  = (const float*)d_in[16];
    const int* edge_index = (const int*)d_in[17];
    const int* edge_type  = (const int*)d_in[18];
    const int* idx        = (const int*)d_in[19];
    float* out = (float*)d_out;

    const int N = NN, E = EE;
    float* ws = (float*)d_ws;
    size_t o = 0;
    float* h      = ws + o;  o += (size_t)N * 128;
    float* stats  = ws + o;  o += 256;
    float* qrel_bias = ws + o; o += 2 * 512;
    int* cnt  = (int*)(ws + o); o += N;
    int* off  = (int*)(ws + o); o += N + 1;
    int* fill = (int*)(ws + o); o += N;
    int* bsum = (int*)(ws + o); o += 256;
    int* pack = (int*)(ws + o); o += E;
    unsigned short* x_bf   = (unsigned short*)(ws + o); o += (size_t)N * 64;
    unsigned short* h_bf   = (unsigned short*)(ws + o); o += (size_t)N * 64;
    unsigned short* k_bf   = (unsigned short*)(ws + o); o += (size_t)N * 64;
    unsigned short* v_bf   = (unsigned short*)(ws + o); o += (size_t)N * 64;
    unsigned short* msg_bf = (unsigned short*)(ws + o); o += (size_t)N * 64;
    unsigned short* qrel_bf = (unsigned short*)(ws + o); o += (size_t)N * 256;
    unsigned short* agg_bf  = (unsigned short*)(ws + o); o += (size_t)N * 256;
    unsigned short* wt_all  = (unsigned short*)(ws + o); o += 7 * 16384 / 2;
    unsigned short* qrel_wt = (unsigned short*)(ws + o); o += 2 * 65536 / 2;
    unsigned short* msg_wt  = (unsigned short*)(ws + o); o += 2 * 65536 / 2;

    const int NB = (N + 255) / 256;
    dim3 g128((N + 127) / 128, 1), g512((N + 127) / 128, 4);

    // ---- CSR build ----
    zero_int_kernel<<<NB, 256, 0, stream>>>(cnt, N);
    hist_kernel<<<(E + 255) / 256, 256, 0, stream>>>(edge_index, cnt, E);
    scan_block_kernel<<<NB, 256, 0, stream>>>(cnt, off, bsum, N);
    scan_bsum_kernel<<<1, 256, 0, stream>>>(bsum, NB);
    scan_add_kernel<<<NB, 256, 0, stream>>>(off, bsum, fill, N, E);
    scatter_kernel<<<(E + 255) / 256, 256, 0, stream>>>(edge_index, edge_type, fill, pack, E);

    // ---- weight prep + x cast ----
    cast_transpose_all<<<7 * 64, 256, 0, stream>>>(proj_w, k_w, v_w, a_w, wt_all);
    qrel_weight_kernel<<<dim3(256, 2), 256, 0, stream>>>(q_w, q_b, a_rel, qrel_wt, qrel_bias);
    msg_weight_kernel<<<dim3(256, 2), 256, 0, stream>>>(m_rel, msg_wt);
    cast_x_kernel<<<(N * 32 + 255) / 256, 256, 0, stream>>>(x, x_bf, N);

    // ---- proj + BN ----
    gemm_bf16<<<g128, 256, 0, stream>>>(x_bf, wt_all, proj_b, h, nullptr, N, 128, 128, 0, nullptr);
    zero_int_kernel<<<1, 256, 0, stream>>>((int*)stats, 256);
    bn_stats_kernel<<<(N + 127) / 128, 128, 0, stream>>>(h, stats, N);
    bn_apply_kernel<<<(N * 32 + 255) / 256, 256, 0, stream>>>(h, h_bf, stats, bn_g, bn_b, N);

    for (int l = 0; l < 2; ++l) {
        unsigned short* kwt = wt_all + 16384 * (1 + l * 3);
        unsigned short* vwt = wt_all + 16384 * (2 + l * 3);
        unsigned short* awt = wt_all + 16384 * (3 + l * 3);
        gemm_bf16<<<g512, 256, 0, stream>>>(h_bf, qrel_wt + (size_t)l * 65536,
                                            qrel_bias + l * 512, nullptr, qrel_bf,
                                            N, 128, 512, 3, nullptr);
        gemm_bf16<<<g128, 256, 0, stream>>>(h_bf, kwt, k_b + l * 128, nullptr, k_bf,
                                            N, 128, 128, 3, nullptr);
        gemm_bf16<<<g128, 256, 0, stream>>>(h_bf, vwt, v_b + l * 128, nullptr, v_bf,
                                            N, 128, 128, 3, nullptr);
        agg_fused_kernel<<<(N + 3) / 4, 256, 0, stream>>>(qrel_bf, k_bf, v_bf, off, pack,
                                                          p_rel + l * 16, agg_bf, N);
        gemm_bf16<<<g128, 256, 0, stream>>>(agg_bf, msg_wt + (size_t)l * 65536, nullptr,
                                            nullptr, msg_bf, N, 512, 128, 2, nullptr);
        gemm_bf16<<<g128, 256, 0, stream>>>(msg_bf, awt, a_b + l * 128, h, h_bf,
                                            N, 128, 128, 1, skip + l);
    }

    gather_kernel<<<(MOUT * 32 + 255) / 256, 256, 0, stream>>>(h, idx, out, MOUT);
}

// Round 4
// 701.494 us; speedup vs baseline: 4.3475x; 1.0789x over previous
//
#include <hip/hip_runtime.h>
#include <math.h>

#define NN 50000
#define EE 600000
#define MOUT 10000
#define DEGCAP 96

typedef short bf16x8 __attribute__((ext_vector_type(8)));
typedef float f32x4 __attribute__((ext_vector_type(4)));

__device__ __forceinline__ unsigned short f2bf(float x) {
    unsigned int u = __float_as_uint(x);
    u = (u + 0x7FFFu + ((u >> 16) & 1u)) >> 16;
    return (unsigned short)u;
}
__device__ __forceinline__ float bf2f(unsigned int b) {
    return __uint_as_float(b << 16);
}

// ============ bf16 MFMA GEMM: C[M,NC] = epilogue(A[M,K] @ Wt[NC,K]^T + bias) ============
// mode 0: Cf = val (fp32)        mode 3: Cb = bf16(val)
// mode 2: Cb = bf16(gelu(val))   mode 1: nv = g*val+(1-g)*Cf; Cf=nv; Cb=bf16(nv)
__global__ __launch_bounds__(256) void gemm_bf16(
    const unsigned short* __restrict__ A, const unsigned short* __restrict__ Wt,
    const float* __restrict__ bias, float* __restrict__ Cf,
    unsigned short* __restrict__ Cb, int M, int K, int NC, int mode,
    const float* __restrict__ skipv)
{
    __shared__ unsigned short As[128 * 40];
    __shared__ unsigned short Bs[128 * 40];
    const int t = threadIdx.x;
    const int wave = t >> 6, lane = t & 63;
    const int quad = lane >> 4, l16 = lane & 15;
    const int row0 = blockIdx.x * 128, col0 = blockIdx.y * 128;
    const int wr = (wave & 1) * 64, wc = (wave >> 1) * 64;
    const int sr = t >> 1, sc = (t & 1) * 16;
    const int grow = row0 + sr;
    const int nk = K >> 5;

    f32x4 acc[4][4];
    #pragma unroll
    for (int i = 0; i < 4; ++i)
        #pragma unroll
        for (int j = 0; j < 4; ++j)
            acc[i][j] = (f32x4){0.f, 0.f, 0.f, 0.f};

    uint4 av0 = make_uint4(0,0,0,0), av1 = av0, bv0, bv1;
    if (grow < M) {
        const uint4* ap = (const uint4*)(A + (size_t)grow * K + sc);
        av0 = ap[0]; av1 = ap[1];
    }
    {
        const uint4* bp = (const uint4*)(Wt + (size_t)(col0 + sr) * K + sc);
        bv0 = bp[0]; bv1 = bp[1];
    }

    for (int it = 0; it < nk; ++it) {
        __syncthreads();
        *(uint4*)(As + sr * 40 + sc)     = av0;
        *(uint4*)(As + sr * 40 + sc + 8) = av1;
        *(uint4*)(Bs + sr * 40 + sc)     = bv0;
        *(uint4*)(Bs + sr * 40 + sc + 8) = bv1;
        __syncthreads();
        if (it + 1 < nk) {          // prefetch next K-tile while MFMAs run
            int kb = (it + 1) * 32;
            if (grow < M) {
                const uint4* ap = (const uint4*)(A + (size_t)grow * K + kb + sc);
                av0 = ap[0]; av1 = ap[1];
            }
            const uint4* bp = (const uint4*)(Wt + (size_t)(col0 + sr) * K + kb + sc);
            bv0 = bp[0]; bv1 = bp[1];
        }
        bf16x8 af[4], bfr[4];
        #pragma unroll
        for (int f = 0; f < 4; ++f) {
            af[f]  = *(const bf16x8*)(As + (wr + f * 16 + l16) * 40 + quad * 8);
            bfr[f] = *(const bf16x8*)(Bs + (wc + f * 16 + l16) * 40 + quad * 8);
        }
        #pragma unroll
        for (int fr = 0; fr < 4; ++fr)
            #pragma unroll
            for (int fc = 0; fc < 4; ++fc)
                acc[fr][fc] = __builtin_amdgcn_mfma_f32_16x16x32_bf16(
                    af[fr], bfr[fc], acc[fr][fc], 0, 0, 0);
    }

    float gate = 0.f;
    if (mode == 1) gate = 1.f / (1.f + __expf(-skipv[0]));
    float b4[4];
    #pragma unroll
    for (int fc = 0; fc < 4; ++fc)
        b4[fc] = bias ? bias[col0 + wc + fc * 16 + l16] : 0.f;
    #pragma unroll
    for (int fr = 0; fr < 4; ++fr) {
        #pragma unroll
        for (int reg = 0; reg < 4; ++reg) {
            int row = row0 + wr + fr * 16 + quad * 4 + reg;
            if (row >= M) continue;
            #pragma unroll
            for (int fc = 0; fc < 4; ++fc) {
                int col = col0 + wc + fc * 16 + l16;
                size_t ci = (size_t)row * NC + col;
                float val = acc[fr][fc][reg] + b4[fc];
                if (mode == 0) {
                    Cf[ci] = val;
                } else if (mode == 3) {
                    Cb[ci] = f2bf(val);
                } else if (mode == 2) {
                    float gl = 0.5f * val * (1.f + erff(val * 0.70710678118654752f));
                    Cb[ci] = f2bf(gl);
                } else {
                    float nv = gate * val + (1.f - gate) * Cf[ci];
                    Cf[ci] = nv;
                    Cb[ci] = f2bf(nv);
                }
            }
        }
    }
}

// ============ weight prep ============
// proj, a_w[0], a_w[1] -> transposed bf16
__global__ __launch_bounds__(256) void cast_transpose_pa(
    const float* __restrict__ proj_w, const float* __restrict__ a_w,
    unsigned short* __restrict__ wt)
{
    int wi = blockIdx.x >> 6;
    int flat = (blockIdx.x & 63) * 256 + threadIdx.x;
    int n = flat >> 7, c = flat & 127;
    const float* src = (wi == 0) ? proj_w : (wi == 1) ? a_w : a_w + 16384;
    wt[(size_t)wi * 16384 + n * 128 + c] = f2bf(src[c * 128 + n]);
}

// fused qkv weight [768][128]: rows 0..511 = qrel (q_w folded with a_rel), 512..639 = k^T, 640..767 = v^T
__global__ __launch_bounds__(256) void qkv_weight_kernel(
    const float* __restrict__ q_w, const float* __restrict__ q_b,
    const float* __restrict__ a_rel,
    const float* __restrict__ k_w, const float* __restrict__ k_b,
    const float* __restrict__ v_w, const float* __restrict__ v_b,
    unsigned short* __restrict__ qkvw, float* __restrict__ fbias)
{
    int l = blockIdx.y;
    int flat = blockIdx.x * 256 + threadIdx.x;   // 768*128
    int nrow = flat >> 7, c = flat & 127;
    unsigned short* wt = qkvw + (size_t)l * 98304;
    float* fb = fbias + l * 768;
    if (nrow < 512) {
        int r = nrow >> 7, hh = (nrow >> 5) & 3, d = nrow & 31;
        const float* qwc = q_w + (size_t)l * 16384 + c * 128 + hh * 32;
        const float* ar  = a_rel + (size_t)(l * 4 + r) * 4096 + hh * 1024 + d * 32;
        float s = 0.f;
        #pragma unroll 8
        for (int e = 0; e < 32; ++e) s += qwc[e] * ar[e];
        wt[(size_t)nrow * 128 + c] = f2bf(s);
        if (c == 0) {
            const float* qb = q_b + l * 128 + hh * 32;
            float b = 0.f;
            #pragma unroll 8
            for (int e = 0; e < 32; ++e) b += qb[e] * ar[e];
            fb[nrow] = b;
        }
    } else if (nrow < 640) {
        int col = nrow - 512;
        wt[(size_t)nrow * 128 + c] = f2bf(k_w[(size_t)l * 16384 + c * 128 + col]);
        if (c == 0) fb[nrow] = k_b[l * 128 + col];
    } else {
        int col = nrow - 640;
        wt[(size_t)nrow * 128 + c] = f2bf(v_w[(size_t)l * 16384 + c * 128 + col]);
        if (c == 0) fb[nrow] = v_b[l * 128 + col];
    }
}

// W_msg_t[(h,e)][(r,h2,d)] = (h2==h) ? m_rel[r,h,d,e] : 0   (128 x 512 bf16)
__global__ __launch_bounds__(256) void msg_weight_kernel(
    const float* __restrict__ m_rel, unsigned short* __restrict__ msg_wt)
{
    int l = blockIdx.y;
    int flat = blockIdx.x * 256 + threadIdx.x;
    int n = flat >> 9, kk = flat & 511;
    int h = n >> 5, e = n & 31;
    int r = kk >> 7, h2 = (kk >> 5) & 3, d = kk & 31;
    float val = (h2 == h) ? m_rel[(size_t)(l * 4 + r) * 4096 + h * 1024 + d * 32 + e] : 0.f;
    msg_wt[(size_t)l * 65536 + (size_t)n * 512 + kk] = f2bf(val);
}

__global__ __launch_bounds__(256) void cast_x_kernel(const float* __restrict__ x,
    unsigned short* __restrict__ xb, int n)
{
    int i = blockIdx.x * 256 + threadIdx.x;
    if (i >= n * 32) return;
    float4 v = ((const float4*)x)[i];
    uint2 pk;
    pk.x = (unsigned int)f2bf(v.x) | ((unsigned int)f2bf(v.y) << 16);
    pk.y = (unsigned int)f2bf(v.z) | ((unsigned int)f2bf(v.w) << 16);
    ((uint2*)xb)[i] = pk;
}

// ============ BatchNorm ============
__global__ __launch_bounds__(128) void bn_stats_kernel(const float* __restrict__ h,
                                                       float* __restrict__ stats, int n)
{
    int c = threadIdx.x;
    int r0 = blockIdx.x * 128;
    int r1 = min(r0 + 128, n);
    float s = 0.f, s2 = 0.f;
    for (int r = r0; r < r1; ++r) {
        float v = h[(size_t)r * 128 + c];
        s += v; s2 += v * v;
    }
    atomicAdd(&stats[c], s);
    atomicAdd(&stats[128 + c], s2);
}

__global__ __launch_bounds__(256) void bn_apply_kernel(float* __restrict__ h,
    unsigned short* __restrict__ hbf, const float* __restrict__ stats,
    const float* __restrict__ gamma, const float* __restrict__ beta, int n)
{
    int i = blockIdx.x * 256 + threadIdx.x;
    if (i >= n * 32) return;
    int c4 = i & 31;
    float invN = 1.f / (float)n;
    float4 v = ((const float4*)h)[i];
    float o[4] = {v.x, v.y, v.z, v.w};
    #pragma unroll
    for (int j = 0; j < 4; ++j) {
        int c = c4 * 4 + j;
        float mu = stats[c] * invN;
        float var = stats[128 + c] * invN - mu * mu;
        o[j] = (o[j] - mu) * rsqrtf(var + 1e-5f) * gamma[c] + beta[c];
    }
    ((float4*)h)[i] = make_float4(o[0], o[1], o[2], o[3]);
    uint2 pk;
    pk.x = (unsigned int)f2bf(o[0]) | ((unsigned int)f2bf(o[1]) << 16);
    pk.y = (unsigned int)f2bf(o[2]) | ((unsigned int)f2bf(o[3]) << 16);
    ((uint2*)hbf)[i] = pk;
}

// ============ CSR build over N*4 segments (seg = dst*4 + rel) ============
__global__ __launch_bounds__(256) void zero_int_kernel(int* __restrict__ p, int n)
{
    int i = blockIdx.x * 256 + threadIdx.x;
    if (i < n) p[i] = 0;
}

__global__ __launch_bounds__(256) void hist_kernel(const int* __restrict__ ei,
    const int* __restrict__ et, int* __restrict__ cnt, int E)
{
    int e = blockIdx.x * 256 + threadIdx.x;
    if (e < E) atomicAdd(&cnt[ei[E + e] * 4 + et[e]], 1);
}

__global__ __launch_bounds__(256) void scan_block_kernel(const int* __restrict__ cnt,
    int* __restrict__ excl, int* __restrict__ bsum, int n)
{
    __shared__ int tmp[256];
    int i = blockIdx.x * 256 + threadIdx.x;
    int v = (i < n) ? cnt[i] : 0;
    tmp[threadIdx.x] = v;
    __syncthreads();
    for (int ofs = 1; ofs < 256; ofs <<= 1) {
        int t = (threadIdx.x >= ofs) ? tmp[threadIdx.x - ofs] : 0;
        __syncthreads();
        tmp[threadIdx.x] += t;
        __syncthreads();
    }
    if (i < n) excl[i] = tmp[threadIdx.x] - v;
    if (threadIdx.x == 255) bsum[blockIdx.x] = tmp[255];
}

// single-block multi-chunk exclusive scan of bsum[nb] with running carry
__global__ __launch_bounds__(256) void scan_bsum_multi(int* __restrict__ bsum, int nb)
{
    __shared__ int tmp[256];
    __shared__ int carry;
    if (threadIdx.x == 0) carry = 0;
    __syncthreads();
    for (int b0 = 0; b0 < nb; b0 += 256) {
        int i = b0 + threadIdx.x;
        int v = (i < nb) ? bsum[i] : 0;
        tmp[threadIdx.x] = v;
        __syncthreads();
        for (int ofs = 1; ofs < 256; ofs <<= 1) {
            int t = (threadIdx.x >= ofs) ? tmp[threadIdx.x - ofs] : 0;
            __syncthreads();
            tmp[threadIdx.x] += t;
            __syncthreads();
        }
        int excl = tmp[threadIdx.x] - v + carry;
        if (i < nb) bsum[i] = excl;
        __syncthreads();
        if (threadIdx.x == 255) carry += tmp[255];
        __syncthreads();
    }
}

__global__ __launch_bounds__(256) void scan_add_kernel(int* __restrict__ excl,
    const int* __restrict__ bsum, int* __restrict__ fill, int n, int total)
{
    int i = blockIdx.x * 256 + threadIdx.x;
    if (i < n) {
        int o = excl[i] + bsum[blockIdx.x];
        excl[i] = o;
        fill[i] = o;
    }
    if (blockIdx.x == 0 && threadIdx.x == 0) excl[n] = total;
}

__global__ __launch_bounds__(256) void scatter_kernel(const int* __restrict__ ei,
    const int* __restrict__ et, int* __restrict__ fill, int* __restrict__ pack, int E)
{
    int e = blockIdx.x * 256 + threadIdx.x;
    if (e >= E) return;
    int seg = ei[E + e] * 4 + et[e];
    int p = atomicAdd(&fill[seg], 1);
    pack[p] = ei[e];
}

// ============ fused per-dst attention, relation-sorted runs, no barriers ============
// qkv row [768] bf16: q_rel(512) | k(128) | v(128). One wave per node; lane owns
// elements 2*lane, 2*lane+1 of 128; h = lane>>4. Per relation run: q in registers,
// max/denom/accum in registers, scores cached in per-wave LDS.
__global__ __launch_bounds__(256) void agg_fused_kernel(
    const unsigned short* __restrict__ qkv,
    const int* __restrict__ off4, const int* __restrict__ pack,
    const float* __restrict__ prel, unsigned short* __restrict__ aggb, int n)
{
    __shared__ float sscore[4][DEGCAP * 4];
    __shared__ int   spack[4][DEGCAP];
    const int wv = threadIdx.x >> 6;
    const int lane = threadIdx.x & 63;
    const int node = blockIdx.x * 4 + wv;
    const int h = lane >> 4;
    if (node >= n) return;                 // no __syncthreads in this kernel

    int off_r[5];
    #pragma unroll
    for (int i = 0; i < 5; ++i)
        off_r[i] = __builtin_amdgcn_readfirstlane(off4[node * 4 + i]);
    const int beg = off_r[0];
    const int deg = off_r[4] - beg;
    const bool cached = deg <= DEGCAP;

    const unsigned int* qrow = (const unsigned int*)(qkv + (size_t)node * 768);
    const float sc = 0.17677669529663687f;   // 1/sqrt(32)

    if (cached) {
        for (int i = lane; i < deg; i += 64) spack[wv][i] = pack[beg + i];
        asm volatile("s_waitcnt vmcnt(0) lgkmcnt(0)" ::: "memory");
    }

    unsigned int outw[4];
    for (int r = 0; r < 4; ++r) {
        unsigned int qu = qrow[r * 64 + lane];
        float pr = prel[r * 4 + h] * sc;
        float qx = bf2f(qu & 0xFFFFu) * pr;
        float qy = bf2f(qu >> 16) * pr;
        float m = -3.4e38f, den = 0.f, ax = 0.f, ay = 0.f;

        if (cached) {
            const int rb = off_r[r] - beg, re = off_r[r + 1] - beg;
            // pass 1: scores + max (q constant -> zero selects)
            for (int i = rb; i < re; ++i) {
                int src = spack[wv][i];
                unsigned int ku = *(const unsigned int*)(qkv + (size_t)src * 768 + 512 + lane * 2);
                float part = qx * bf2f(ku & 0xFFFFu) + qy * bf2f(ku >> 16);
                part += __shfl_xor(part, 1); part += __shfl_xor(part, 2);
                part += __shfl_xor(part, 4); part += __shfl_xor(part, 8);
                if ((lane & 15) == 0) sscore[wv][i * 4 + h] = part;
                m = fmaxf(m, part);
            }
            asm volatile("s_waitcnt lgkmcnt(0)" ::: "memory");
            // pass 2: exp + denom + weighted V
            for (int i = rb; i < re; ++i) {
                int src = spack[wv][i];
                unsigned int vu = *(const unsigned int*)(qkv + (size_t)src * 768 + 640 + lane * 2);
                float e = __expf(sscore[wv][i * 4 + h] - m);
                den += e;
                ax += e * bf2f(vu & 0xFFFFu);
                ay += e * bf2f(vu >> 16);
            }
        } else {   // rare giant-degree fallback: stream pack, recompute scores
            for (int p = off_r[r]; p < off_r[r + 1]; ++p) {
                int src = __builtin_amdgcn_readfirstlane(pack[p]);
                unsigned int ku = *(const unsigned int*)(qkv + (size_t)src * 768 + 512 + lane * 2);
                float part = qx * bf2f(ku & 0xFFFFu) + qy * bf2f(ku >> 16);
                part += __shfl_xor(part, 1); part += __shfl_xor(part, 2);
                part += __shfl_xor(part, 4); part += __shfl_xor(part, 8);
                m = fmaxf(m, part);
            }
            for (int p = off_r[r]; p < off_r[r + 1]; ++p) {
                int src = __builtin_amdgcn_readfirstlane(pack[p]);
                unsigned int ku = *(const unsigned int*)(qkv + (size_t)src * 768 + 512 + lane * 2);
                unsigned int vu = *(const unsigned int*)(qkv + (size_t)src * 768 + 640 + lane * 2);
                float part = qx * bf2f(ku & 0xFFFFu) + qy * bf2f(ku >> 16);
                part += __shfl_xor(part, 1); part += __shfl_xor(part, 2);
                part += __shfl_xor(part, 4); part += __shfl_xor(part, 8);
                float e = __expf(part - m);
                den += e;
                ax += e * bf2f(vu & 0xFFFFu);
                ay += e * bf2f(vu >> 16);
            }
        }
        float inv = den > 0.f ? 1.f / den : 0.f;
        outw[r] = (unsigned int)f2bf(ax * inv) | ((unsigned int)f2bf(ay * inv) << 16);
    }
    unsigned int* op = (unsigned int*)(aggb + (size_t)node * 512);
    #pragma unroll
    for (int r = 0; r < 4; ++r) op[r * 64 + lane] = outw[r];
}

// ============ final gather ============
__global__ __launch_bounds__(256) void gather_kernel(const float* __restrict__ h,
    const int* __restrict__ idx, float* __restrict__ out, int m)
{
    int i = blockIdx.x * 256 + threadIdx.x;
    if (i >= m * 32) return;
    int row = i >> 5, c4 = i & 31;
    ((float4*)out)[i] = ((const float4*)(h + (size_t)idx[row] * 128))[c4];
}

extern "C" void kernel_launch(void* const* d_in, const int* in_sizes, int n_in,
                              void* d_out, int out_size, void* d_ws, size_t ws_size,
                              hipStream_t stream)
{
    const float* x      = (const float*)d_in[0];
    const float* proj_w = (const float*)d_in[1];
    const float* proj_b = (const float*)d_in[2];
    const float* bn_g   = (const float*)d_in[3];
    const float* bn_b   = (const float*)d_in[4];
    const float* q_w    = (const float*)d_in[5];
    const float* q_b    = (const float*)d_in[6];
    const float* k_w    = (const float*)d_in[7];
    const float* k_b    = (const float*)d_in[8];
    const float* v_w    = (const float*)d_in[9];
    const float* v_b    = (const float*)d_in[10];
    const float* a_w    = (const float*)d_in[11];
    const float* a_b    = (const float*)d_in[12];
    const float* skip   = (const float*)d_in[13];
    const float* a_rel  = (const float*)d_in[14];
    const float* m_rel  = (const float*)d_in[15];
    const float* p_rel  = (const float*)d_in[16];
    const int* edge_index = (const int*)d_in[17];
    const int* edge_type  = (const int*)d_in[18];
    const int* idx        = (const int*)d_in[19];
    float* out = (float*)d_out;

    const int N = NN, E = EE, NT = NN * 4;
    float* ws = (float*)d_ws;
    size_t o = 0;
    float* h      = ws + o;  o += (size_t)N * 128;
    float* stats  = ws + o;  o += 256;
    float* fbias  = ws + o;  o += 2 * 768;
    int* cnt  = (int*)(ws + o); o += NT;
    int* off4 = (int*)(ws + o); o += NT + 1;
    int* fill = (int*)(ws + o); o += NT;
    int* bsum = (int*)(ws + o); o += 1024;
    int* pack = (int*)(ws + o); o += E;
    unsigned short* x_bf   = (unsigned short*)(ws + o); o += (size_t)N * 64;
    unsigned short* h_bf   = (unsigned short*)(ws + o); o += (size_t)N * 64;
    unsigned short* msg_bf = (unsigned short*)(ws + o); o += (size_t)N * 64;
    unsigned short* qkv_bf = (unsigned short*)(ws + o); o += (size_t)N * 384;
    unsigned short* agg_bf = (unsigned short*)(ws + o); o += (size_t)N * 256;
    unsigned short* wt_pa  = (unsigned short*)(ws + o); o += 3 * 16384 / 2;
    unsigned short* qkvw   = (unsigned short*)(ws + o); o += 2 * 98304 / 2;
    unsigned short* msg_wt = (unsigned short*)(ws + o); o += 2 * 65536 / 2;

    const int NB4 = (NT + 255) / 256;
    dim3 g128((N + 127) / 128, 1), g768((N + 127) / 128, 6);

    // ---- CSR build over (dst, rel) segments ----
    zero_int_kernel<<<NB4, 256, 0, stream>>>(cnt, NT);
    hist_kernel<<<(E + 255) / 256, 256, 0, stream>>>(edge_index, edge_type, cnt, E);
    scan_block_kernel<<<NB4, 256, 0, stream>>>(cnt, off4, bsum, NT);
    scan_bsum_multi<<<1, 256, 0, stream>>>(bsum, NB4);
    scan_add_kernel<<<NB4, 256, 0, stream>>>(off4, bsum, fill, NT, E);
    scatter_kernel<<<(E + 255) / 256, 256, 0, stream>>>(edge_index, edge_type, fill, pack, E);

    // ---- weight prep + x cast ----
    cast_transpose_pa<<<3 * 64, 256, 0, stream>>>(proj_w, a_w, wt_pa);
    qkv_weight_kernel<<<dim3(384, 2), 256, 0, stream>>>(q_w, q_b, a_rel, k_w, k_b,
                                                        v_w, v_b, qkvw, fbias);
    msg_weight_kernel<<<dim3(256, 2), 256, 0, stream>>>(m_rel, msg_wt);
    cast_x_kernel<<<(N * 32 + 255) / 256, 256, 0, stream>>>(x, x_bf, N);

    // ---- proj + BN ----
    gemm_bf16<<<g128, 256, 0, stream>>>(x_bf, wt_pa, proj_b, h, nullptr, N, 128, 128, 0, nullptr);
    zero_int_kernel<<<1, 256, 0, stream>>>((int*)stats, 256);
    bn_stats_kernel<<<(N + 127) / 128, 128, 0, stream>>>(h, stats, N);
    bn_apply_kernel<<<(N * 32 + 255) / 256, 256, 0, stream>>>(h, h_bf, stats, bn_g, bn_b, N);

    for (int l = 0; l < 2; ++l) {
        gemm_bf16<<<g768, 256, 0, stream>>>(h_bf, qkvw + (size_t)l * 98304,
                                            fbias + l * 768, nullptr, qkv_bf,
                                            N, 128, 768, 3, nullptr);
        agg_fused_kernel<<<(N + 3) / 4, 256, 0, stream>>>(qkv_bf, off4, pack,
                                                          p_rel + l * 16, agg_bf, N);
        gemm_bf16<<<g128, 256, 0, stream>>>(agg_bf, msg_wt + (size_t)l * 65536, nullptr,
                                            nullptr, msg_bf, N, 512, 128, 2, nullptr);
        gemm_bf16<<<g128, 256, 0, stream>>>(msg_bf, wt_pa + (size_t)(1 + l) * 16384,
                                            a_b + l * 128, h, h_bf, N, 128, 128, 1, skip + l);
    }

    gather_kernel<<<(MOUT * 32 + 255) / 256, 256, 0, stream>>>(h, idx, out, MOUT);
}

// Round 5
// 622.678 us; speedup vs baseline: 4.8978x; 1.1266x over previous
//
#include <hip/hip_runtime.h>
#include <math.h>

#define NN 50000
#define EE 600000
#define MOUT 10000
#define DEGCAP 384

typedef short bf16x8 __attribute__((ext_vector_type(8)));
typedef float f32x4 __attribute__((ext_vector_type(4)));

__device__ __forceinline__ unsigned short f2bf(float x) {
    unsigned int u = __float_as_uint(x);
    u = (u + 0x7FFFu + ((u >> 16) & 1u)) >> 16;
    return (unsigned short)u;
}
__device__ __forceinline__ float bf2f(unsigned int b) {
    return __uint_as_float(b << 16);
}

// ============ bf16 MFMA GEMM: C[M,NC] = epilogue(A[M,K] @ Wt[NC,K]^T + bias) ============
// mode 0: Cf = val (fp32)        mode 3: Cb = bf16(val)
// mode 2: Cb = bf16(gelu(val))   mode 1: nv = g*val+(1-g)*Cf; Cf=nv; Cb=bf16(nv)
__global__ __launch_bounds__(256) void gemm_bf16(
    const unsigned short* __restrict__ A, const unsigned short* __restrict__ Wt,
    const float* __restrict__ bias, float* __restrict__ Cf,
    unsigned short* __restrict__ Cb, int M, int K, int NC, int mode,
    const float* __restrict__ skipv)
{
    __shared__ unsigned short As[128 * 40];
    __shared__ unsigned short Bs[128 * 40];
    const int t = threadIdx.x;
    const int wave = t >> 6, lane = t & 63;
    const int quad = lane >> 4, l16 = lane & 15;
    const int row0 = blockIdx.x * 128, col0 = blockIdx.y * 128;
    const int wr = (wave & 1) * 64, wc = (wave >> 1) * 64;
    const int sr = t >> 1, sc = (t & 1) * 16;
    const int grow = row0 + sr;
    const int nk = K >> 5;

    f32x4 acc[4][4];
    #pragma unroll
    for (int i = 0; i < 4; ++i)
        #pragma unroll
        for (int j = 0; j < 4; ++j)
            acc[i][j] = (f32x4){0.f, 0.f, 0.f, 0.f};

    uint4 av0 = make_uint4(0,0,0,0), av1 = av0, bv0, bv1;
    if (grow < M) {
        const uint4* ap = (const uint4*)(A + (size_t)grow * K + sc);
        av0 = ap[0]; av1 = ap[1];
    }
    {
        const uint4* bp = (const uint4*)(Wt + (size_t)(col0 + sr) * K + sc);
        bv0 = bp[0]; bv1 = bp[1];
    }

    for (int it = 0; it < nk; ++it) {
        __syncthreads();
        *(uint4*)(As + sr * 40 + sc)     = av0;
        *(uint4*)(As + sr * 40 + sc + 8) = av1;
        *(uint4*)(Bs + sr * 40 + sc)     = bv0;
        *(uint4*)(Bs + sr * 40 + sc + 8) = bv1;
        __syncthreads();
        if (it + 1 < nk) {          // prefetch next K-tile while MFMAs run
            int kb = (it + 1) * 32;
            if (grow < M) {
                const uint4* ap = (const uint4*)(A + (size_t)grow * K + kb + sc);
                av0 = ap[0]; av1 = ap[1];
            }
            const uint4* bp = (const uint4*)(Wt + (size_t)(col0 + sr) * K + kb + sc);
            bv0 = bp[0]; bv1 = bp[1];
        }
        bf16x8 af[4], bfr[4];
        #pragma unroll
        for (int f = 0; f < 4; ++f) {
            af[f]  = *(const bf16x8*)(As + (wr + f * 16 + l16) * 40 + quad * 8);
            bfr[f] = *(const bf16x8*)(Bs + (wc + f * 16 + l16) * 40 + quad * 8);
        }
        #pragma unroll
        for (int fr = 0; fr < 4; ++fr)
            #pragma unroll
            for (int fc = 0; fc < 4; ++fc)
                acc[fr][fc] = __builtin_amdgcn_mfma_f32_16x16x32_bf16(
                    af[fr], bfr[fc], acc[fr][fc], 0, 0, 0);
    }

    float gate = 0.f;
    if (mode == 1) gate = 1.f / (1.f + __expf(-skipv[0]));
    float b4[4];
    #pragma unroll
    for (int fc = 0; fc < 4; ++fc)
        b4[fc] = bias ? bias[col0 + wc + fc * 16 + l16] : 0.f;
    #pragma unroll
    for (int fr = 0; fr < 4; ++fr) {
        #pragma unroll
        for (int reg = 0; reg < 4; ++reg) {
            int row = row0 + wr + fr * 16 + quad * 4 + reg;
            if (row >= M) continue;
            #pragma unroll
            for (int fc = 0; fc < 4; ++fc) {
                int col = col0 + wc + fc * 16 + l16;
                size_t ci = (size_t)row * NC + col;
                float val = acc[fr][fc][reg] + b4[fc];
                if (mode == 0) {
                    Cf[ci] = val;
                } else if (mode == 3) {
                    Cb[ci] = f2bf(val);
                } else if (mode == 2) {
                    float gl = 0.5f * val * (1.f + erff(val * 0.70710678118654752f));
                    Cb[ci] = f2bf(gl);
                } else {
                    float nv = gate * val + (1.f - gate) * Cf[ci];
                    Cf[ci] = nv;
                    Cb[ci] = f2bf(nv);
                }
            }
        }
    }
}

// ============ weight prep ============
__global__ __launch_bounds__(256) void cast_transpose_pa(
    const float* __restrict__ proj_w, const float* __restrict__ a_w,
    unsigned short* __restrict__ wt)
{
    int wi = blockIdx.x >> 6;
    int flat = (blockIdx.x & 63) * 256 + threadIdx.x;
    int n = flat >> 7, c = flat & 127;
    const float* src = (wi == 0) ? proj_w : (wi == 1) ? a_w : a_w + 16384;
    wt[(size_t)wi * 16384 + n * 128 + c] = f2bf(src[c * 128 + n]);
}

// fused qkv weight [768][128]: rows 0..511 = qrel (q_w folded with a_rel), 512..639 = k^T, 640..767 = v^T
__global__ __launch_bounds__(256) void qkv_weight_kernel(
    const float* __restrict__ q_w, const float* __restrict__ q_b,
    const float* __restrict__ a_rel,
    const float* __restrict__ k_w, const float* __restrict__ k_b,
    const float* __restrict__ v_w, const float* __restrict__ v_b,
    unsigned short* __restrict__ qkvw, float* __restrict__ fbias)
{
    int l = blockIdx.y;
    int flat = blockIdx.x * 256 + threadIdx.x;   // 768*128
    int nrow = flat >> 7, c = flat & 127;
    unsigned short* wt = qkvw + (size_t)l * 98304;
    float* fb = fbias + l * 768;
    if (nrow < 512) {
        int r = nrow >> 7, hh = (nrow >> 5) & 3, d = nrow & 31;
        const float* qwc = q_w + (size_t)l * 16384 + c * 128 + hh * 32;
        const float* ar  = a_rel + (size_t)(l * 4 + r) * 4096 + hh * 1024 + d * 32;
        float s = 0.f;
        #pragma unroll 8
        for (int e = 0; e < 32; ++e) s += qwc[e] * ar[e];
        wt[(size_t)nrow * 128 + c] = f2bf(s);
        if (c == 0) {
            const float* qb = q_b + l * 128 + hh * 32;
            float b = 0.f;
            #pragma unroll 8
            for (int e = 0; e < 32; ++e) b += qb[e] * ar[e];
            fb[nrow] = b;
        }
    } else if (nrow < 640) {
        int col = nrow - 512;
        wt[(size_t)nrow * 128 + c] = f2bf(k_w[(size_t)l * 16384 + c * 128 + col]);
        if (c == 0) fb[nrow] = k_b[l * 128 + col];
    } else {
        int col = nrow - 640;
        wt[(size_t)nrow * 128 + c] = f2bf(v_w[(size_t)l * 16384 + c * 128 + col]);
        if (c == 0) fb[nrow] = v_b[l * 128 + col];
    }
}

// W_msg_t[(h,e)][(r,h2,d)] = (h2==h) ? m_rel[r,h,d,e] : 0   (128 x 512 bf16)
__global__ __launch_bounds__(256) void msg_weight_kernel(
    const float* __restrict__ m_rel, unsigned short* __restrict__ msg_wt)
{
    int l = blockIdx.y;
    int flat = blockIdx.x * 256 + threadIdx.x;
    int n = flat >> 9, kk = flat & 511;
    int h = n >> 5, e = n & 31;
    int r = kk >> 7, h2 = (kk >> 5) & 3, d = kk & 31;
    float val = (h2 == h) ? m_rel[(size_t)(l * 4 + r) * 4096 + h * 1024 + d * 32 + e] : 0.f;
    msg_wt[(size_t)l * 65536 + (size_t)n * 512 + kk] = f2bf(val);
}

__global__ __launch_bounds__(256) void cast_x_kernel(const float* __restrict__ x,
    unsigned short* __restrict__ xb, int n)
{
    int i = blockIdx.x * 256 + threadIdx.x;
    if (i >= n * 32) return;
    float4 v = ((const float4*)x)[i];
    uint2 pk;
    pk.x = (unsigned int)f2bf(v.x) | ((unsigned int)f2bf(v.y) << 16);
    pk.y = (unsigned int)f2bf(v.z) | ((unsigned int)f2bf(v.w) << 16);
    ((uint2*)xb)[i] = pk;
}

// ============ BatchNorm ============
__global__ __launch_bounds__(128) void bn_stats_kernel(const float* __restrict__ h,
                                                       float* __restrict__ stats, int n)
{
    int c = threadIdx.x;
    int r0 = blockIdx.x * 128;
    int r1 = min(r0 + 128, n);
    float s = 0.f, s2 = 0.f;
    for (int r = r0; r < r1; ++r) {
        float v = h[(size_t)r * 128 + c];
        s += v; s2 += v * v;
    }
    atomicAdd(&stats[c], s);
    atomicAdd(&stats[128 + c], s2);
}

__global__ __launch_bounds__(256) void bn_apply_kernel(float* __restrict__ h,
    unsigned short* __restrict__ hbf, const float* __restrict__ stats,
    const float* __restrict__ gamma, const float* __restrict__ beta, int n)
{
    int i = blockIdx.x * 256 + threadIdx.x;
    if (i >= n * 32) return;
    int c4 = i & 31;
    float invN = 1.f / (float)n;
    float4 v = ((const float4*)h)[i];
    float o[4] = {v.x, v.y, v.z, v.w};
    #pragma unroll
    for (int j = 0; j < 4; ++j) {
        int c = c4 * 4 + j;
        float mu = stats[c] * invN;
        float var = stats[128 + c] * invN - mu * mu;
        o[j] = (o[j] - mu) * rsqrtf(var + 1e-5f) * gamma[c] + beta[c];
    }
    ((float4*)h)[i] = make_float4(o[0], o[1], o[2], o[3]);
    uint2 pk;
    pk.x = (unsigned int)f2bf(o[0]) | ((unsigned int)f2bf(o[1]) << 16);
    pk.y = (unsigned int)f2bf(o[2]) | ((unsigned int)f2bf(o[3]) << 16);
    ((uint2*)hbf)[i] = pk;
}

// ============ CSR build over N*4 segments (seg = dst*4 + rel) ============
__global__ __launch_bounds__(256) void zero_int_kernel(int* __restrict__ p, int n)
{
    int i = blockIdx.x * 256 + threadIdx.x;
    if (i < n) p[i] = 0;
}

__global__ __launch_bounds__(256) void hist_kernel(const int* __restrict__ ei,
    const int* __restrict__ et, int* __restrict__ cnt, int E)
{
    int e = blockIdx.x * 256 + threadIdx.x;
    if (e < E) atomicAdd(&cnt[ei[E + e] * 4 + et[e]], 1);
}

__global__ __launch_bounds__(256) void scan_block_kernel(const int* __restrict__ cnt,
    int* __restrict__ excl, int* __restrict__ bsum, int n)
{
    __shared__ int tmp[256];
    int i = blockIdx.x * 256 + threadIdx.x;
    int v = (i < n) ? cnt[i] : 0;
    tmp[threadIdx.x] = v;
    __syncthreads();
    for (int ofs = 1; ofs < 256; ofs <<= 1) {
        int t = (threadIdx.x >= ofs) ? tmp[threadIdx.x - ofs] : 0;
        __syncthreads();
        tmp[threadIdx.x] += t;
        __syncthreads();
    }
    if (i < n) excl[i] = tmp[threadIdx.x] - v;
    if (threadIdx.x == 255) bsum[blockIdx.x] = tmp[255];
}

// single-block multi-chunk exclusive scan of bsum[nb] with running carry
__global__ __launch_bounds__(256) void scan_bsum_multi(int* __restrict__ bsum, int nb)
{
    __shared__ int tmp[256];
    __shared__ int carry;
    if (threadIdx.x == 0) carry = 0;
    __syncthreads();
    for (int b0 = 0; b0 < nb; b0 += 256) {
        int i = b0 + threadIdx.x;
        int v = (i < nb) ? bsum[i] : 0;
        tmp[threadIdx.x] = v;
        __syncthreads();
        for (int ofs = 1; ofs < 256; ofs <<= 1) {
            int t = (threadIdx.x >= ofs) ? tmp[threadIdx.x - ofs] : 0;
            __syncthreads();
            tmp[threadIdx.x] += t;
            __syncthreads();
        }
        int excl = tmp[threadIdx.x] - v + carry;
        if (i < nb) bsum[i] = excl;
        __syncthreads();
        if (threadIdx.x == 255) carry += tmp[255];
        __syncthreads();
    }
}

__global__ __launch_bounds__(256) void scan_add_kernel(int* __restrict__ excl,
    const int* __restrict__ bsum, int* __restrict__ fill, int n, int total)
{
    int i = blockIdx.x * 256 + threadIdx.x;
    if (i < n) {
        int o = excl[i] + bsum[blockIdx.x];
        excl[i] = o;
        fill[i] = o;
    }
    if (blockIdx.x == 0 && threadIdx.x == 0) excl[n] = total;
}

__global__ __launch_bounds__(256) void scatter_kernel(const int* __restrict__ ei,
    const int* __restrict__ et, int* __restrict__ fill, int* __restrict__ pack, int E)
{
    int e = blockIdx.x * 256 + threadIdx.x;
    if (e >= E) return;
    int seg = ei[E + e] * 4 + et[e];
    int p = atomicAdd(&fill[seg], 1);
    pack[p] = ei[e];
}

// ============ fused per-dst attention: relation-sorted runs, ONLINE softmax ============
// Single pass per relation run: k and v loads issue together (2x MLP), unroll-2 over
// edges (4 loads in flight). Running max + rescale (flash-style) in registers.
__device__ __forceinline__ void online_upd(float s, float vx, float vy,
    float& m, float& den, float& ax, float& ay)
{
    float mn = fmaxf(m, s);
    float scale = __expf(m - mn);    // 0 on first edge (m = -3.4e38)
    float e = __expf(s - mn);
    den = den * scale + e;
    ax = ax * scale + e * vx;
    ay = ay * scale + e * vy;
    m = mn;
}

__global__ __launch_bounds__(256) void agg_fused_kernel(
    const unsigned short* __restrict__ qkv,
    const int* __restrict__ off4, const int* __restrict__ pack,
    const float* __restrict__ prel, unsigned short* __restrict__ aggb, int n)
{
    __shared__ int spack[4][DEGCAP];
    const int wv = threadIdx.x >> 6;
    const int lane = threadIdx.x & 63;
    const int node = blockIdx.x * 4 + wv;
    const int h = lane >> 4;
    if (node >= n) return;                 // no __syncthreads in this kernel

    int off_r[5];
    #pragma unroll
    for (int i = 0; i < 5; ++i)
        off_r[i] = __builtin_amdgcn_readfirstlane(off4[node * 4 + i]);
    const int beg = off_r[0];
    const int deg = off_r[4] - beg;
    const bool cached = deg <= DEGCAP;

    const unsigned int* qrow = (const unsigned int*)(qkv + (size_t)node * 768);
    const float sc = 0.17677669529663687f;   // 1/sqrt(32)

    if (cached) {
        for (int i = lane; i < deg; i += 64) spack[wv][i] = pack[beg + i];
        asm volatile("s_waitcnt vmcnt(0) lgkmcnt(0)" ::: "memory");
    }

    unsigned int outw[4];
    for (int r = 0; r < 4; ++r) {
        unsigned int qu = qrow[r * 64 + lane];
        float pr = prel[r * 4 + h] * sc;
        float qx = bf2f(qu & 0xFFFFu) * pr;
        float qy = bf2f(qu >> 16) * pr;
        float m = -3.4e38f, den = 0.f, ax = 0.f, ay = 0.f;

        if (cached) {
            const int rb = off_r[r] - beg, re = off_r[r + 1] - beg;
            int i = rb;
            for (; i + 2 <= re; i += 2) {
                int s0 = spack[wv][i], s1 = spack[wv][i + 1];
                const unsigned short* row0 = qkv + (size_t)s0 * 768;
                const unsigned short* row1 = qkv + (size_t)s1 * 768;
                unsigned int ku0 = *(const unsigned int*)(row0 + 512 + lane * 2);
                unsigned int vu0 = *(const unsigned int*)(row0 + 640 + lane * 2);
                unsigned int ku1 = *(const unsigned int*)(row1 + 512 + lane * 2);
                unsigned int vu1 = *(const unsigned int*)(row1 + 640 + lane * 2);
                float p0 = qx * bf2f(ku0 & 0xFFFFu) + qy * bf2f(ku0 >> 16);
                float p1 = qx * bf2f(ku1 & 0xFFFFu) + qy * bf2f(ku1 >> 16);
                p0 += __shfl_xor(p0, 1); p1 += __shfl_xor(p1, 1);
                p0 += __shfl_xor(p0, 2); p1 += __shfl_xor(p1, 2);
                p0 += __shfl_xor(p0, 4); p1 += __shfl_xor(p1, 4);
                p0 += __shfl_xor(p0, 8); p1 += __shfl_xor(p1, 8);
                online_upd(p0, bf2f(vu0 & 0xFFFFu), bf2f(vu0 >> 16), m, den, ax, ay);
                online_upd(p1, bf2f(vu1 & 0xFFFFu), bf2f(vu1 >> 16), m, den, ax, ay);
            }
            if (i < re) {
                int s0 = spack[wv][i];
                const unsigned short* row0 = qkv + (size_t)s0 * 768;
                unsigned int ku0 = *(const unsigned int*)(row0 + 512 + lane * 2);
                unsigned int vu0 = *(const unsigned int*)(row0 + 640 + lane * 2);
                float p0 = qx * bf2f(ku0 & 0xFFFFu) + qy * bf2f(ku0 >> 16);
                p0 += __shfl_xor(p0, 1); p0 += __shfl_xor(p0, 2);
                p0 += __shfl_xor(p0, 4); p0 += __shfl_xor(p0, 8);
                online_upd(p0, bf2f(vu0 & 0xFFFFu), bf2f(vu0 >> 16), m, den, ax, ay);
            }
        } else {   // giant-degree fallback: stream pack scalar-wise
            for (int p = off_r[r]; p < off_r[r + 1]; ++p) {
                int src = __builtin_amdgcn_readfirstlane(pack[p]);
                const unsigned short* row0 = qkv + (size_t)src * 768;
                unsigned int ku0 = *(const unsigned int*)(row0 + 512 + lane * 2);
                unsigned int vu0 = *(const unsigned int*)(row0 + 640 + lane * 2);
                float p0 = qx * bf2f(ku0 & 0xFFFFu) + qy * bf2f(ku0 >> 16);
                p0 += __shfl_xor(p0, 1); p0 += __shfl_xor(p0, 2);
                p0 += __shfl_xor(p0, 4); p0 += __shfl_xor(p0, 8);
                online_upd(p0, bf2f(vu0 & 0xFFFFu), bf2f(vu0 >> 16), m, den, ax, ay);
            }
        }
        float inv = den > 0.f ? 1.f / den : 0.f;
        outw[r] = (unsigned int)f2bf(ax * inv) | ((unsigned int)f2bf(ay * inv) << 16);
    }
    unsigned int* op = (unsigned int*)(aggb + (size_t)node * 512);
    #pragma unroll
    for (int r = 0; r < 4; ++r) op[r * 64 + lane] = outw[r];
}

// ============ final gather ============
__global__ __launch_bounds__(256) void gather_kernel(const float* __restrict__ h,
    const int* __restrict__ idx, float* __restrict__ out, int m)
{
    int i = blockIdx.x * 256 + threadIdx.x;
    if (i >= m * 32) return;
    int row = i >> 5, c4 = i & 31;
    ((float4*)out)[i] = ((const float4*)(h + (size_t)idx[row] * 128))[c4];
}

extern "C" void kernel_launch(void* const* d_in, const int* in_sizes, int n_in,
                              void* d_out, int out_size, void* d_ws, size_t ws_size,
                              hipStream_t stream)
{
    const float* x      = (const float*)d_in[0];
    const float* proj_w = (const float*)d_in[1];
    const float* proj_b = (const float*)d_in[2];
    const float* bn_g   = (const float*)d_in[3];
    const float* bn_b   = (const float*)d_in[4];
    const float* q_w    = (const float*)d_in[5];
    const float* q_b    = (const float*)d_in[6];
    const float* k_w    = (const float*)d_in[7];
    const float* k_b    = (const float*)d_in[8];
    const float* v_w    = (const float*)d_in[9];
    const float* v_b    = (const float*)d_in[10];
    const float* a_w    = (const float*)d_in[11];
    const float* a_b    = (const float*)d_in[12];
    const float* skip   = (const float*)d_in[13];
    const float* a_rel  = (const float*)d_in[14];
    const float* m_rel  = (const float*)d_in[15];
    const float* p_rel  = (const float*)d_in[16];
    const int* edge_index = (const int*)d_in[17];
    const int* edge_type  = (const int*)d_in[18];
    const int* idx        = (const int*)d_in[19];
    float* out = (float*)d_out;

    const int N = NN, E = EE, NT = NN * 4;
    float* ws = (float*)d_ws;
    size_t o = 0;
    float* h      = ws + o;  o += (size_t)N * 128;
    float* stats  = ws + o;  o += 256;
    float* fbias  = ws + o;  o += 2 * 768;
    int* cnt  = (int*)(ws + o); o += NT;
    int* off4 = (int*)(ws + o); o += NT + 1;
    int* fill = (int*)(ws + o); o += NT;
    int* bsum = (int*)(ws + o); o += 1024;
    int* pack = (int*)(ws + o); o += E;
    unsigned short* x_bf   = (unsigned short*)(ws + o); o += (size_t)N * 64;
    unsigned short* h_bf   = (unsigned short*)(ws + o); o += (size_t)N * 64;
    unsigned short* msg_bf = (unsigned short*)(ws + o); o += (size_t)N * 64;
    unsigned short* qkv_bf = (unsigned short*)(ws + o); o += (size_t)N * 384;
    unsigned short* agg_bf = (unsigned short*)(ws + o); o += (size_t)N * 256;
    unsigned short* wt_pa  = (unsigned short*)(ws + o); o += 3 * 16384 / 2;
    unsigned short* qkvw   = (unsigned short*)(ws + o); o += 2 * 98304 / 2;
    unsigned short* msg_wt = (unsigned short*)(ws + o); o += 2 * 65536 / 2;

    const int NB4 = (NT + 255) / 256;
    dim3 g128((N + 127) / 128, 1), g768((N + 127) / 128, 6);

    // ---- CSR build over (dst, rel) segments ----
    zero_int_kernel<<<NB4, 256, 0, stream>>>(cnt, NT);
    hist_kernel<<<(E + 255) / 256, 256, 0, stream>>>(edge_index, edge_type, cnt, E);
    scan_block_kernel<<<NB4, 256, 0, stream>>>(cnt, off4, bsum, NT);
    scan_bsum_multi<<<1, 256, 0, stream>>>(bsum, NB4);
    scan_add_kernel<<<NB4, 256, 0, stream>>>(off4, bsum, fill, NT, E);
    scatter_kernel<<<(E + 255) / 256, 256, 0, stream>>>(edge_index, edge_type, fill, pack, E);

    // ---- weight prep + x cast ----
    cast_transpose_pa<<<3 * 64, 256, 0, stream>>>(proj_w, a_w, wt_pa);
    qkv_weight_kernel<<<dim3(384, 2), 256, 0, stream>>>(q_w, q_b, a_rel, k_w, k_b,
                                                        v_w, v_b, qkvw, fbias);
    msg_weight_kernel<<<dim3(256, 2), 256, 0, stream>>>(m_rel, msg_wt);
    cast_x_kernel<<<(N * 32 + 255) / 256, 256, 0, stream>>>(x, x_bf, N);

    // ---- proj + BN ----
    gemm_bf16<<<g128, 256, 0, stream>>>(x_bf, wt_pa, proj_b, h, nullptr, N, 128, 128, 0, nullptr);
    zero_int_kernel<<<1, 256, 0, stream>>>((int*)stats, 256);
    bn_stats_kernel<<<(N + 127) / 128, 128, 0, stream>>>(h, stats, N);
    bn_apply_kernel<<<(N * 32 + 255) / 256, 256, 0, stream>>>(h, h_bf, stats, bn_g, bn_b, N);

    for (int l = 0; l < 2; ++l) {
        gemm_bf16<<<g768, 256, 0, stream>>>(h_bf, qkvw + (size_t)l * 98304,
                                            fbias + l * 768, nullptr, qkv_bf,
                                            N, 128, 768, 3, nullptr);
        agg_fused_kernel<<<(N + 3) / 4, 256, 0, stream>>>(qkv_bf, off4, pack,
                                                          p_rel + l * 16, agg_bf, N);
        gemm_bf16<<<g128, 256, 0, stream>>>(agg_bf, msg_wt + (size_t)l * 65536, nullptr,
                                            nullptr, msg_bf, N, 512, 128, 2, nullptr);
        gemm_bf16<<<g128, 256, 0, stream>>>(msg_bf, wt_pa + (size_t)(1 + l) * 16384,
                                            a_b + l * 128, h, h_bf, N, 128, 128, 1, skip + l);
    }

    gather_kernel<<<(MOUT * 32 + 255) / 256, 256, 0, stream>>>(h, idx, out, MOUT);
}